// Round 1
// baseline (3345.601 us; speedup 1.0000x reference)
//
#include <hip/hip_runtime.h>

constexpr int NB = 1024;   // graphs
constexpr int NN = 64;     // nodes per graph
constexpr int ND = 128;    // feature dim (D == G == 128)
constexpr int NE = 512;    // edges per graph
constexpr int FEAT_F = 12288;  // 3*16*16*16

// ---------------- fused GCN layer: per-graph matmul + normalized aggregation ----------------
__global__ __launch_bounds__(512)
void gcn_kernel(const float* __restrict__ h_in, const float* __restrict__ W,
                const float* __restrict__ bias,
                const int* __restrict__ esrc, const int* __restrict__ edst,
                float* __restrict__ outp, int relu_in)
{
    __shared__ float w_s[ND * ND];        // 64KB
    __shared__ float h_s[NN * ND];        // 32KB, reused as output accumulator
    __shared__ float m_s[NN * ND];        // 32KB
    __shared__ unsigned char src_s[NE];
    __shared__ unsigned char dst_s[NE];
    __shared__ int   cnt_s[NN];
    __shared__ float dis_s[NN];

    const int b = blockIdx.x;
    const int tid = threadIdx.x;

    if (tid < NN) cnt_s[tid] = 1;          // self-loop
    __syncthreads();

    // one edge per thread (NE == 512 == blockDim)
    {
        const int s = esrc[b * NE + tid] & (NN - 1);
        const int d = edst[b * NE + tid] & (NN - 1);
        src_s[tid] = (unsigned char)s;
        dst_s[tid] = (unsigned char)d;
        atomicAdd(&cnt_s[d], 1);
    }
    for (int i = tid; i < ND * ND; i += 512) w_s[i] = W[i];
    for (int i = tid; i < NN * ND; i += 512) {
        const float v = h_in[(size_t)b * (NN * ND) + i];
        h_s[i] = relu_in ? fmaxf(v, 0.f) : v;
    }
    __syncthreads();

    if (tid < NN) dis_s[tid] = rsqrtf((float)cnt_s[tid]);

    // m = h @ W : each thread computes 4 rows x 4 cols
    const int jc = (tid & 31) * 4;
    const int rg = tid >> 5;               // 0..15
    float acc[4][4];
    #pragma unroll
    for (int ii = 0; ii < 4; ii++)
        #pragma unroll
        for (int jj = 0; jj < 4; jj++) acc[ii][jj] = 0.f;

    for (int k4 = 0; k4 < ND / 4; k4++) {
        float4 hv[4], wv[4];
        #pragma unroll
        for (int ii = 0; ii < 4; ii++)
            hv[ii] = *(const float4*)&h_s[(rg * 4 + ii) * ND + k4 * 4];
        #pragma unroll
        for (int kk = 0; kk < 4; kk++)
            wv[kk] = *(const float4*)&w_s[(k4 * 4 + kk) * ND + jc];
        #pragma unroll
        for (int ii = 0; ii < 4; ii++) {
            const float hk[4] = {hv[ii].x, hv[ii].y, hv[ii].z, hv[ii].w};
            #pragma unroll
            for (int kk = 0; kk < 4; kk++) {
                acc[ii][0] += hk[kk] * wv[kk].x;
                acc[ii][1] += hk[kk] * wv[kk].y;
                acc[ii][2] += hk[kk] * wv[kk].z;
                acc[ii][3] += hk[kk] * wv[kk].w;
            }
        }
    }
    #pragma unroll
    for (int ii = 0; ii < 4; ii++)
        *(float4*)&m_s[(rg * 4 + ii) * ND + jc] =
            make_float4(acc[ii][0], acc[ii][1], acc[ii][2], acc[ii][3]);
    __syncthreads();

    // scale rows by dis (separable norm) and init accumulator with self term
    float* out_s = h_s;
    for (int i = tid; i < NN * ND; i += 512) {
        const float v = m_s[i] * dis_s[i >> 7];
        m_s[i]  = v;
        out_s[i] = v;
    }
    __syncthreads();

    // edge aggregation: 128 feature-owners x 4 edge groups, LDS float atomics
    {
        const int f = tid & 127;
        const int g = tid >> 7;            // 0..3
        for (int e = g; e < NE; e += 4)
            atomicAdd(&out_s[(int)dst_s[e] * ND + f], m_s[(int)src_s[e] * ND + f]);
    }
    __syncthreads();

    const float bf = bias[tid & 127];
    for (int i = tid; i < NN * ND; i += 512)
        outp[(size_t)b * (NN * ND) + i] = out_s[i] * dis_s[i >> 7] + bf;
}

// ---------------- per-graph similarity: S = Q (64x128) x C^T ----------------
__global__ __launch_bounds__(256)
void sims_kernel(const float* __restrict__ fq, const float* __restrict__ fc,
                 float* __restrict__ S)
{
    __shared__ float q_s[64 * 132];
    __shared__ float c_s[64 * 132];
    const int b = blockIdx.x, tid = threadIdx.x;
    for (int i = tid; i < NN * ND; i += 256) {
        const int r = i >> 7, k = i & 127;
        q_s[r * 132 + k] = fq[(size_t)b * (NN * ND) + i];
        c_s[r * 132 + k] = fc[(size_t)b * (NN * ND) + i];
    }
    __syncthreads();
    const int j = tid & 63, ig = tid >> 6;     // ig 0..3
    float acc[16];
    #pragma unroll
    for (int ii = 0; ii < 16; ii++) acc[ii] = 0.f;
    for (int k4 = 0; k4 < 32; k4++) {
        const float4 cv = *(const float4*)&c_s[j * 132 + k4 * 4];
        #pragma unroll
        for (int ii = 0; ii < 16; ii++) {
            const float4 qv = *(const float4*)&q_s[(ig * 16 + ii) * 132 + k4 * 4];
            acc[ii] += qv.x * cv.x + qv.y * cv.y + qv.z * cv.z + qv.w * cv.w;
        }
    }
    for (int ii = 0; ii < 16; ii++)
        S[(size_t)b * 4096 + (ig * 16 + ii) * 64 + j] = acc[ii];
}

// ---------------- fused conv1+relu+pool + conv2+relu+pool ----------------
__global__ __launch_bounds__(256)
void conv_kernel(const float* __restrict__ simsb,
                 const float* __restrict__ c1w, const float* __restrict__ c1b,
                 const float* __restrict__ c2w, const float* __restrict__ c2b,
                 float* __restrict__ feat)
{
    __shared__ float img[68 * 68];       // 64x64 padded by 2
    __shared__ float p1[8 * 36 * 36];    // 8x32x32 padded by 2
    __shared__ float w1s[8 * 25];
    __shared__ float b1s[8];
    __shared__ float w2s[16 * 8 * 28];   // rows padded to 28 for alignment
    __shared__ float b2s[16];

    const int b = blockIdx.x, l = blockIdx.y, tid = threadIdx.x;

    for (int i = tid; i < 68 * 68; i += 256) img[i] = 0.f;
    for (int i = tid; i < 8 * 36 * 36; i += 256) p1[i] = 0.f;
    for (int i = tid; i < 200; i += 256) w1s[i] = c1w[l * 200 + i];
    if (tid < 8)  b1s[tid] = c1b[l * 8 + tid];
    for (int i = tid; i < 16 * 8 * 25; i += 256) {
        const int r = i / 25, cc = i - r * 25;
        w2s[r * 28 + cc] = c2w[l * 3200 + i];
    }
    if (tid < 16) b2s[tid] = c2b[l * 16 + tid];
    __syncthreads();
    for (int i = tid; i < 4096; i += 256) {
        const int y = i >> 6, x = i & 63;
        img[(y + 2) * 68 + (x + 2)] = simsb[((size_t)l * NB + b) * 4096 + i];
    }
    __syncthreads();

    // conv1 (1->8, 5x5, pad2) + relu + 2x2 maxpool
    for (int c = 0; c < 8; c++) {
        float wr[25];
        #pragma unroll
        for (int t = 0; t < 25; t++) wr[t] = w1s[c * 25 + t];
        const float bb = b1s[c];
        #pragma unroll
        for (int q = 0; q < 4; q++) {
            const int o = q * 256 + tid;          // 0..1023
            const int yy = o >> 5, xx = o & 31;
            float patch[36];
            #pragma unroll
            for (int r = 0; r < 6; r++)
                #pragma unroll
                for (int cc = 0; cc < 6; cc++)
                    patch[r * 6 + cc] = img[(2 * yy + r) * 68 + 2 * xx + cc];
            float mval = 0.f;                     // relu floor
            #pragma unroll
            for (int dy = 0; dy < 2; dy++)
                #pragma unroll
                for (int dx = 0; dx < 2; dx++) {
                    float a = bb;
                    #pragma unroll
                    for (int ky = 0; ky < 5; ky++)
                        #pragma unroll
                        for (int kx = 0; kx < 5; kx++)
                            a += patch[(dy + ky) * 6 + dx + kx] * wr[ky * 5 + kx];
                    mval = fmaxf(mval, a);
                }
            p1[c * 1296 + (yy + 2) * 36 + (xx + 2)] = mval;
        }
    }
    __syncthreads();

    // conv2 (8->16, 5x5, pad2) + relu + 2x2 maxpool, write feat layout
    const int yy = tid >> 4, xx = tid & 15;
    for (int cg = 0; cg < 4; cg++) {
        float acc[4][4];
        #pragma unroll
        for (int c4 = 0; c4 < 4; c4++) {
            const float bb = b2s[cg * 4 + c4];
            #pragma unroll
            for (int p = 0; p < 4; p++) acc[c4][p] = bb;
        }
        for (int ci = 0; ci < 8; ci++) {
            float patch[36];
            #pragma unroll
            for (int r = 0; r < 6; r++)
                #pragma unroll
                for (int cc = 0; cc < 6; cc++)
                    patch[r * 6 + cc] = p1[ci * 1296 + (2 * yy + r) * 36 + 2 * xx + cc];
            #pragma unroll
            for (int c4 = 0; c4 < 4; c4++) {
                const float* wp = &w2s[((cg * 4 + c4) * 8 + ci) * 28];
                float wr[25];
                #pragma unroll
                for (int t = 0; t < 25; t++) wr[t] = wp[t];
                #pragma unroll
                for (int dy = 0; dy < 2; dy++)
                    #pragma unroll
                    for (int dx = 0; dx < 2; dx++) {
                        const int p = dy * 2 + dx;
                        #pragma unroll
                        for (int ky = 0; ky < 5; ky++)
                            #pragma unroll
                            for (int kx = 0; kx < 5; kx++)
                                acc[c4][p] += patch[(dy + ky) * 6 + dx + kx] * wr[ky * 5 + kx];
                    }
            }
        }
        #pragma unroll
        for (int c4 = 0; c4 < 4; c4++) {
            float m = 0.f;
            #pragma unroll
            for (int p = 0; p < 4; p++) m = fmaxf(m, acc[c4][p]);
            const int c = cg * 4 + c4;
            feat[(size_t)b * FEAT_F + (((size_t)l * 16 + c) * 16 + yy) * 16 + xx] = m;
        }
    }
}

// ---------------- linear 1024x12288 @ 12288x512, split-K with atomics ----------------
__global__ __launch_bounds__(256)
void lin_kernel(const float* __restrict__ feat, const float* __restrict__ lw,
                float* __restrict__ hacc)
{
    __shared__ float a_s[64 * 17];
    __shared__ float b_s[16 * 68];
    const int m0 = blockIdx.x * 64, n0 = blockIdx.y * 64;
    const int k0 = blockIdx.z * 1536;
    const int tid = threadIdx.x;
    const int tm = tid >> 4, tn = tid & 15;
    float acc[4][4];
    #pragma unroll
    for (int ii = 0; ii < 4; ii++)
        #pragma unroll
        for (int jj = 0; jj < 4; jj++) acc[ii][jj] = 0.f;

    for (int ks = 0; ks < 96; ks++) {
        const int kc = k0 + ks * 16;
        for (int i = tid; i < 1024; i += 256) {
            const int r = i >> 4, cc = i & 15;
            a_s[r * 17 + cc] = feat[(size_t)(m0 + r) * FEAT_F + kc + cc];
        }
        for (int i = tid; i < 1024; i += 256) {
            const int r = i >> 6, cc = i & 63;
            b_s[r * 68 + cc] = lw[(size_t)(kc + r) * 512 + n0 + cc];
        }
        __syncthreads();
        #pragma unroll
        for (int kk = 0; kk < 16; kk++) {
            float av[4];
            #pragma unroll
            for (int ii = 0; ii < 4; ii++) av[ii] = a_s[(tm * 4 + ii) * 17 + kk];
            const float4 bv = *(const float4*)&b_s[kk * 68 + tn * 4];
            #pragma unroll
            for (int ii = 0; ii < 4; ii++) {
                acc[ii][0] += av[ii] * bv.x;
                acc[ii][1] += av[ii] * bv.y;
                acc[ii][2] += av[ii] * bv.z;
                acc[ii][3] += av[ii] * bv.w;
            }
        }
        __syncthreads();
    }
    #pragma unroll
    for (int ii = 0; ii < 4; ii++)
        #pragma unroll
        for (int jj = 0; jj < 4; jj++)
            atomicAdd(&hacc[(size_t)(m0 + tm * 4 + ii) * 512 + n0 + tn * 4 + jj],
                      acc[ii][jj]);
}

// ---------------- bias + relu + score dot ----------------
__global__ __launch_bounds__(256)
void score_kernel(const float* __restrict__ hacc, const float* __restrict__ lb,
                  const float* __restrict__ sw, const float* __restrict__ sb,
                  float* __restrict__ outp)
{
    const int b = blockIdx.x, tid = threadIdx.x;
    float v = 0.f;
    for (int j = tid; j < 512; j += 256)
        v += fmaxf(hacc[(size_t)b * 512 + j] + lb[j], 0.f) * sw[j];
    #pragma unroll
    for (int off = 32; off > 0; off >>= 1) v += __shfl_down(v, off);
    __shared__ float red[4];
    if ((tid & 63) == 0) red[tid >> 6] = v;
    __syncthreads();
    if (tid == 0) outp[b] = red[0] + red[1] + red[2] + red[3] + sb[0];
}

extern "C" void kernel_launch(void* const* d_in, const int* in_sizes, int n_in,
                              void* d_out, int out_size, void* d_ws, size_t ws_size,
                              hipStream_t stream)
{
    const float* x_q = (const float*)d_in[0];
    const float* x_c = (const float*)d_in[1];
    const float* gw[3] = {(const float*)d_in[2], (const float*)d_in[4], (const float*)d_in[6]};
    const float* gb[3] = {(const float*)d_in[3], (const float*)d_in[5], (const float*)d_in[7]};
    const float* c1w = (const float*)d_in[8];
    const float* c1b = (const float*)d_in[9];
    const float* c2w = (const float*)d_in[10];
    const float* c2b = (const float*)d_in[11];
    const float* lw  = (const float*)d_in[12];
    const float* lb  = (const float*)d_in[13];
    const float* sw  = (const float*)d_in[14];
    const float* sb  = (const float*)d_in[15];
    const int* eq = (const int*)d_in[16];
    const int* ec = (const int*)d_in[17];

    float* ws = (float*)d_ws;
    float* q0 = ws;
    float* q1 = q0 + (size_t)NB * NN * ND;
    float* c0 = q1 + (size_t)NB * NN * ND;
    float* c1 = c0 + (size_t)NB * NN * ND;
    float* simsb = c1 + (size_t)NB * NN * ND;              // 3*NB*64*64
    float* feat  = simsb + (size_t)3 * NB * NN * NN;       // NB*12288
    float* hacc  = feat + (size_t)NB * FEAT_F;             // NB*512
    float* outf = (float*)d_out;

    const int* esq = eq;
    const int* edq = eq + (size_t)NB * NE;
    const int* esc = ec;
    const int* edc = ec + (size_t)NB * NE;

    gcn_kernel<<<NB, 512, 0, stream>>>(x_q, gw[0], gb[0], esq, edq, q0, 0);
    gcn_kernel<<<NB, 512, 0, stream>>>(x_c, gw[0], gb[0], esc, edc, c0, 0);
    sims_kernel<<<NB, 256, 0, stream>>>(q0, c0, simsb);
    gcn_kernel<<<NB, 512, 0, stream>>>(q0, gw[1], gb[1], esq, edq, q1, 1);
    gcn_kernel<<<NB, 512, 0, stream>>>(c0, gw[1], gb[1], esc, edc, c1, 1);
    sims_kernel<<<NB, 256, 0, stream>>>(q1, c1, simsb + (size_t)NB * NN * NN);
    gcn_kernel<<<NB, 512, 0, stream>>>(q1, gw[2], gb[2], esq, edq, q0, 1);
    gcn_kernel<<<NB, 512, 0, stream>>>(c1, gw[2], gb[2], esc, edc, c0, 1);
    sims_kernel<<<NB, 256, 0, stream>>>(q0, c0, simsb + (size_t)2 * NB * NN * NN);

    conv_kernel<<<dim3(NB, 3), 256, 0, stream>>>(simsb, c1w, c1b, c2w, c2b, feat);

    hipMemsetAsync(hacc, 0, (size_t)NB * 512 * sizeof(float), stream);
    lin_kernel<<<dim3(16, 8, 8), 256, 0, stream>>>(feat, lw, hacc);
    score_kernel<<<NB, 256, 0, stream>>>(hacc, lb, sw, sb, outf);
}

// Round 5
// 1288.088 us; speedup vs baseline: 2.5973x; 2.5973x over previous
//
#include <hip/hip_runtime.h>

constexpr int NB = 1024;   // graphs
constexpr int NN = 64;     // nodes per graph
constexpr int ND = 128;    // feature dim (D == G == 128)
constexpr int NE = 512;    // edges per graph
constexpr int FEAT_F = 12288;  // 3*16*16*16

// ---------------- build normalized adjacency Â per (graph, side) ----------------
// Â[d][s] = dis[d]*dis[s]*mult(s->d), diagonal += dis[d]^2 (self loop),
// deg[d] = 1 + in-edge count. Â is layer-invariant: build once, reuse 3x.
__global__ __launch_bounds__(256)
void adj_kernel(const int* __restrict__ esq, const int* __restrict__ edq,
                const int* __restrict__ esc, const int* __restrict__ edc,
                float* __restrict__ Aq, float* __restrict__ Ac)
{
    __shared__ float A[NN * NN];
    __shared__ float dis[NN];
    const int b = blockIdx.x, side = blockIdx.y, tid = threadIdx.x;
    const int* es = side ? esc : esq;
    const int* ed = side ? edc : edq;
    float* Aout = side ? Ac : Aq;

    for (int i = tid; i < NN * NN; i += 256) A[i] = 0.f;
    __syncthreads();
    for (int e = tid; e < NE; e += 256) {
        const int s = es[b * NE + e] & (NN - 1);
        const int d = ed[b * NE + e] & (NN - 1);
        atomicAdd(&A[d * NN + s], 1.0f);
    }
    __syncthreads();
    if (tid < NN) {
        float sum = 1.0f;                       // self loop
        for (int s = 0; s < NN; s++) sum += A[tid * NN + s];
        dis[tid] = rsqrtf(sum);
    }
    __syncthreads();
    for (int i = tid; i < NN * NN; i += 256) {
        const int d = i >> 6, s = i & 63;
        float v = A[i];
        if (d == s) v += 1.0f;                  // self loop
        Aout[(size_t)b * (NN * NN) + i] = dis[d] * v * dis[s];
    }
}

// ---------------- fused GCN layer: out = Â @ (relu?(H) @ W) + b, both sides ----------------
__global__ __launch_bounds__(512)
void gcn_kernel(const float* __restrict__ hq, const float* __restrict__ hc,
                const float* __restrict__ Aq, const float* __restrict__ Ac,
                const float* __restrict__ W, const float* __restrict__ bias,
                float* __restrict__ outq, float* __restrict__ outc, int relu_in)
{
    __shared__ float w_s[ND * ND];     // 64KB
    __shared__ float h_s[NN * ND];     // 32KB
    __shared__ float m_s[NN * ND];     // 32KB
    __shared__ float a_s[NN * NN];     // 16KB   -> 144KB total, 1 block/CU

    const int b = blockIdx.x, side = blockIdx.y, tid = threadIdx.x;
    const float* h_in = side ? hc : hq;
    const float* A = side ? Ac : Aq;
    float* outp = side ? outc : outq;

    for (int i = tid; i < ND * ND; i += 512) w_s[i] = W[i];
    for (int i = tid; i < NN * ND; i += 512) {
        const float v = h_in[(size_t)b * (NN * ND) + i];
        h_s[i] = relu_in ? fmaxf(v, 0.f) : v;
    }
    for (int i = tid; i < NN * NN; i += 512)
        a_s[i] = A[(size_t)b * (NN * NN) + i];
    __syncthreads();

    const int rg = tid >> 5;            // 0..15 -> rows rg*4..rg*4+3
    const int jc = (tid & 31) * 4;      // cols jc..jc+3

    // M = H @ W
    float acc[4][4];
    #pragma unroll
    for (int ii = 0; ii < 4; ii++)
        #pragma unroll
        for (int jj = 0; jj < 4; jj++) acc[ii][jj] = 0.f;
    for (int k4 = 0; k4 < ND / 4; k4++) {
        float4 wv[4];
        #pragma unroll
        for (int kk = 0; kk < 4; kk++)
            wv[kk] = *(const float4*)&w_s[(k4 * 4 + kk) * ND + jc];
        #pragma unroll
        for (int ii = 0; ii < 4; ii++) {
            const float4 hv = *(const float4*)&h_s[(rg * 4 + ii) * ND + k4 * 4];
            acc[ii][0] += hv.x * wv[0].x + hv.y * wv[1].x + hv.z * wv[2].x + hv.w * wv[3].x;
            acc[ii][1] += hv.x * wv[0].y + hv.y * wv[1].y + hv.z * wv[2].y + hv.w * wv[3].y;
            acc[ii][2] += hv.x * wv[0].z + hv.y * wv[1].z + hv.z * wv[2].z + hv.w * wv[3].z;
            acc[ii][3] += hv.x * wv[0].w + hv.y * wv[1].w + hv.z * wv[2].w + hv.w * wv[3].w;
        }
    }
    #pragma unroll
    for (int ii = 0; ii < 4; ii++)
        *(float4*)&m_s[(rg * 4 + ii) * ND + jc] =
            make_float4(acc[ii][0], acc[ii][1], acc[ii][2], acc[ii][3]);
    __syncthreads();

    // out = Â @ M + bias
    float acc2[4][4];
    #pragma unroll
    for (int ii = 0; ii < 4; ii++)
        #pragma unroll
        for (int jj = 0; jj < 4; jj++) acc2[ii][jj] = 0.f;
    for (int k4 = 0; k4 < NN / 4; k4++) {
        float4 mv[4];
        #pragma unroll
        for (int kk = 0; kk < 4; kk++)
            mv[kk] = *(const float4*)&m_s[(k4 * 4 + kk) * ND + jc];
        #pragma unroll
        for (int ii = 0; ii < 4; ii++) {
            const float4 av = *(const float4*)&a_s[(rg * 4 + ii) * NN + k4 * 4];
            acc2[ii][0] += av.x * mv[0].x + av.y * mv[1].x + av.z * mv[2].x + av.w * mv[3].x;
            acc2[ii][1] += av.x * mv[0].y + av.y * mv[1].y + av.z * mv[2].y + av.w * mv[3].y;
            acc2[ii][2] += av.x * mv[0].z + av.y * mv[1].z + av.z * mv[2].z + av.w * mv[3].z;
            acc2[ii][3] += av.x * mv[0].w + av.y * mv[1].w + av.z * mv[2].w + av.w * mv[3].w;
        }
    }
    const float4 bv = *(const float4*)&bias[jc];
    #pragma unroll
    for (int ii = 0; ii < 4; ii++) {
        float4 o = make_float4(acc2[ii][0] + bv.x, acc2[ii][1] + bv.y,
                               acc2[ii][2] + bv.z, acc2[ii][3] + bv.w);
        *(float4*)&outp[(size_t)b * (NN * ND) + (rg * 4 + ii) * ND + jc] = o;
    }
}

// ---------------- per-graph similarity: S = Q (64x128) x C^T ----------------
__global__ __launch_bounds__(256)
void sims_kernel(const float* __restrict__ fq, const float* __restrict__ fc,
                 float* __restrict__ S)
{
    __shared__ float q_s[64 * 132];
    __shared__ float c_s[64 * 132];
    const int b = blockIdx.x, tid = threadIdx.x;
    for (int i = tid; i < NN * ND; i += 256) {
        const int r = i >> 7, k = i & 127;
        q_s[r * 132 + k] = fq[(size_t)b * (NN * ND) + i];
        c_s[r * 132 + k] = fc[(size_t)b * (NN * ND) + i];
    }
    __syncthreads();
    const int j = tid & 63, ig = tid >> 6;     // ig 0..3
    float acc[16];
    #pragma unroll
    for (int ii = 0; ii < 16; ii++) acc[ii] = 0.f;
    for (int k4 = 0; k4 < 32; k4++) {
        const float4 cv = *(const float4*)&c_s[j * 132 + k4 * 4];
        #pragma unroll
        for (int ii = 0; ii < 16; ii++) {
            const float4 qv = *(const float4*)&q_s[(ig * 16 + ii) * 132 + k4 * 4];
            acc[ii] += qv.x * cv.x + qv.y * cv.y + qv.z * cv.z + qv.w * cv.w;
        }
    }
    for (int ii = 0; ii < 16; ii++)
        S[(size_t)b * 4096 + (ig * 16 + ii) * 64 + j] = acc[ii];
}

// ---------------- fused conv1+relu+pool + conv2+relu+pool ----------------
__global__ __launch_bounds__(256)
void conv_kernel(const float* __restrict__ simsb,
                 const float* __restrict__ c1w, const float* __restrict__ c1b,
                 const float* __restrict__ c2w, const float* __restrict__ c2b,
                 float* __restrict__ feat)
{
    __shared__ float img[68 * 68];       // 64x64 padded by 2
    __shared__ float p1[8 * 36 * 36];    // 8x32x32 padded by 2
    __shared__ float w1s[8 * 25];
    __shared__ float b1s[8];
    __shared__ float w2s[16 * 8 * 28];   // rows padded to 28 for alignment
    __shared__ float b2s[16];

    const int b = blockIdx.x, l = blockIdx.y, tid = threadIdx.x;

    for (int i = tid; i < 68 * 68; i += 256) img[i] = 0.f;
    for (int i = tid; i < 8 * 36 * 36; i += 256) p1[i] = 0.f;
    for (int i = tid; i < 200; i += 256) w1s[i] = c1w[l * 200 + i];
    if (tid < 8)  b1s[tid] = c1b[l * 8 + tid];
    for (int i = tid; i < 16 * 8 * 25; i += 256) {
        const int r = i / 25, cc = i - r * 25;
        w2s[r * 28 + cc] = c2w[l * 3200 + i];
    }
    if (tid < 16) b2s[tid] = c2b[l * 16 + tid];
    __syncthreads();
    for (int i = tid; i < 4096; i += 256) {
        const int y = i >> 6, x = i & 63;
        img[(y + 2) * 68 + (x + 2)] = simsb[((size_t)l * NB + b) * 4096 + i];
    }
    __syncthreads();

    // conv1 (1->8, 5x5, pad2) + relu + 2x2 maxpool
    for (int c = 0; c < 8; c++) {
        float wr[25];
        #pragma unroll
        for (int t = 0; t < 25; t++) wr[t] = w1s[c * 25 + t];
        const float bb = b1s[c];
        #pragma unroll
        for (int q = 0; q < 4; q++) {
            const int o = q * 256 + tid;          // 0..1023
            const int yy = o >> 5, xx = o & 31;
            float patch[36];
            #pragma unroll
            for (int r = 0; r < 6; r++)
                #pragma unroll
                for (int cc = 0; cc < 6; cc++)
                    patch[r * 6 + cc] = img[(2 * yy + r) * 68 + 2 * xx + cc];
            float mval = 0.f;                     // relu floor
            #pragma unroll
            for (int dy = 0; dy < 2; dy++)
                #pragma unroll
                for (int dx = 0; dx < 2; dx++) {
                    float a = bb;
                    #pragma unroll
                    for (int ky = 0; ky < 5; ky++)
                        #pragma unroll
                        for (int kx = 0; kx < 5; kx++)
                            a += patch[(dy + ky) * 6 + dx + kx] * wr[ky * 5 + kx];
                    mval = fmaxf(mval, a);
                }
            p1[c * 1296 + (yy + 2) * 36 + (xx + 2)] = mval;
        }
    }
    __syncthreads();

    // conv2 (8->16, 5x5, pad2) + relu + 2x2 maxpool, write feat layout
    const int yy = tid >> 4, xx = tid & 15;
    for (int cg = 0; cg < 4; cg++) {
        float acc[4][4];
        #pragma unroll
        for (int c4 = 0; c4 < 4; c4++) {
            const float bb = b2s[cg * 4 + c4];
            #pragma unroll
            for (int p = 0; p < 4; p++) acc[c4][p] = bb;
        }
        for (int ci = 0; ci < 8; ci++) {
            float patch[36];
            #pragma unroll
            for (int r = 0; r < 6; r++)
                #pragma unroll
                for (int cc = 0; cc < 6; cc++)
                    patch[r * 6 + cc] = p1[ci * 1296 + (2 * yy + r) * 36 + 2 * xx + cc];
            #pragma unroll
            for (int c4 = 0; c4 < 4; c4++) {
                const float* wp = &w2s[((cg * 4 + c4) * 8 + ci) * 28];
                float wr[25];
                #pragma unroll
                for (int t = 0; t < 25; t++) wr[t] = wp[t];
                #pragma unroll
                for (int dy = 0; dy < 2; dy++)
                    #pragma unroll
                    for (int dx = 0; dx < 2; dx++) {
                        const int p = dy * 2 + dx;
                        #pragma unroll
                        for (int ky = 0; ky < 5; ky++)
                            #pragma unroll
                            for (int kx = 0; kx < 5; kx++)
                                acc[c4][p] += patch[(dy + ky) * 6 + dx + kx] * wr[ky * 5 + kx];
                    }
            }
        }
        #pragma unroll
        for (int c4 = 0; c4 < 4; c4++) {
            float m = 0.f;
            #pragma unroll
            for (int p = 0; p < 4; p++) m = fmaxf(m, acc[c4][p]);
            const int c = cg * 4 + c4;
            feat[(size_t)b * FEAT_F + (((size_t)l * 16 + c) * 16 + yy) * 16 + xx] = m;
        }
    }
}

// ---------------- linear 1024x12288 @ 12288x512, split-K with atomics ----------------
__global__ __launch_bounds__(256)
void lin_kernel(const float* __restrict__ feat, const float* __restrict__ lw,
                float* __restrict__ hacc)
{
    __shared__ float a_s[64 * 17];
    __shared__ float b_s[16 * 68];
    const int m0 = blockIdx.x * 64, n0 = blockIdx.y * 64;
    const int k0 = blockIdx.z * 1536;
    const int tid = threadIdx.x;
    const int tm = tid >> 4, tn = tid & 15;
    float acc[4][4];
    #pragma unroll
    for (int ii = 0; ii < 4; ii++)
        #pragma unroll
        for (int jj = 0; jj < 4; jj++) acc[ii][jj] = 0.f;

    for (int ks = 0; ks < 96; ks++) {
        const int kc = k0 + ks * 16;
        for (int i = tid; i < 1024; i += 256) {
            const int r = i >> 4, cc = i & 15;
            a_s[r * 17 + cc] = feat[(size_t)(m0 + r) * FEAT_F + kc + cc];
        }
        for (int i = tid; i < 1024; i += 256) {
            const int r = i >> 6, cc = i & 63;
            b_s[r * 68 + cc] = lw[(size_t)(kc + r) * 512 + n0 + cc];
        }
        __syncthreads();
        #pragma unroll
        for (int kk = 0; kk < 16; kk++) {
            float av[4];
            #pragma unroll
            for (int ii = 0; ii < 4; ii++) av[ii] = a_s[(tm * 4 + ii) * 17 + kk];
            const float4 bv = *(const float4*)&b_s[kk * 68 + tn * 4];
            #pragma unroll
            for (int ii = 0; ii < 4; ii++) {
                acc[ii][0] += av[ii] * bv.x;
                acc[ii][1] += av[ii] * bv.y;
                acc[ii][2] += av[ii] * bv.z;
                acc[ii][3] += av[ii] * bv.w;
            }
        }
        __syncthreads();
    }
    #pragma unroll
    for (int ii = 0; ii < 4; ii++)
        #pragma unroll
        for (int jj = 0; jj < 4; jj++)
            atomicAdd(&hacc[(size_t)(m0 + tm * 4 + ii) * 512 + n0 + tn * 4 + jj],
                      acc[ii][jj]);
}

// ---------------- bias + relu + score dot ----------------
__global__ __launch_bounds__(256)
void score_kernel(const float* __restrict__ hacc, const float* __restrict__ lb,
                  const float* __restrict__ sw, const float* __restrict__ sb,
                  float* __restrict__ outp)
{
    const int b = blockIdx.x, tid = threadIdx.x;
    float v = 0.f;
    for (int j = tid; j < 512; j += 256)
        v += fmaxf(hacc[(size_t)b * 512 + j] + lb[j], 0.f) * sw[j];
    #pragma unroll
    for (int off = 32; off > 0; off >>= 1) v += __shfl_down(v, off);
    __shared__ float red[4];
    if ((tid & 63) == 0) red[tid >> 6] = v;
    __syncthreads();
    if (tid == 0) outp[b] = red[0] + red[1] + red[2] + red[3] + sb[0];
}

extern "C" void kernel_launch(void* const* d_in, const int* in_sizes, int n_in,
                              void* d_out, int out_size, void* d_ws, size_t ws_size,
                              hipStream_t stream)
{
    const float* x_q = (const float*)d_in[0];
    const float* x_c = (const float*)d_in[1];
    const float* gw[3] = {(const float*)d_in[2], (const float*)d_in[4], (const float*)d_in[6]};
    const float* gb[3] = {(const float*)d_in[3], (const float*)d_in[5], (const float*)d_in[7]};
    const float* c1w = (const float*)d_in[8];
    const float* c1b = (const float*)d_in[9];
    const float* c2w = (const float*)d_in[10];
    const float* c2b = (const float*)d_in[11];
    const float* lw  = (const float*)d_in[12];
    const float* lb  = (const float*)d_in[13];
    const float* sw  = (const float*)d_in[14];
    const float* sb  = (const float*)d_in[15];
    const int* eq = (const int*)d_in[16];
    const int* ec = (const int*)d_in[17];

    // Workspace layout (floats). Total distinct = 55,050,240 floats = 210 MiB.
    // feat ALIASES q1/c1: q1/c1 are dead after the 3rd gcn launch consumes
    // them; conv_kernel (which writes feat) runs strictly after on the same
    // stream. Keeps ws below the 256 MiB that round-2's +Aq/Ac layout blew.
    float* ws = (float*)d_ws;
    float* q0 = ws;                                        // 8.39M
    float* c0 = q0 + (size_t)NB * NN * ND;                 // 8.39M
    float* q1 = c0 + (size_t)NB * NN * ND;                 // 8.39M  } contiguous
    float* c1 = q1 + (size_t)NB * NN * ND;                 // 8.39M  } 16.78M
    float* simsb = c1 + (size_t)NB * NN * ND;              // 12.58M (3*NB*4096)
    float* hacc  = simsb + (size_t)3 * NB * NN * NN;       // 0.52M
    float* Aq    = hacc + (size_t)NB * 512;                // 4.19M
    float* Ac    = Aq + (size_t)NB * NN * NN;              // 4.19M
    float* feat  = q1;                                     // alias: 12.58M < 16.78M
    float* outf = (float*)d_out;

    const int* esq = eq;
    const int* edq = eq + (size_t)NB * NE;
    const int* esc = ec;
    const int* edc = ec + (size_t)NB * NE;

    adj_kernel<<<dim3(NB, 2), 256, 0, stream>>>(esq, edq, esc, edc, Aq, Ac);

    gcn_kernel<<<dim3(NB, 2), 512, 0, stream>>>(x_q, x_c, Aq, Ac, gw[0], gb[0], q0, c0, 0);
    sims_kernel<<<NB, 256, 0, stream>>>(q0, c0, simsb);
    gcn_kernel<<<dim3(NB, 2), 512, 0, stream>>>(q0, c0, Aq, Ac, gw[1], gb[1], q1, c1, 1);
    sims_kernel<<<NB, 256, 0, stream>>>(q1, c1, simsb + (size_t)NB * NN * NN);
    gcn_kernel<<<dim3(NB, 2), 512, 0, stream>>>(q1, c1, Aq, Ac, gw[2], gb[2], q0, c0, 1);
    sims_kernel<<<NB, 256, 0, stream>>>(q0, c0, simsb + (size_t)2 * NB * NN * NN);

    conv_kernel<<<dim3(NB, 3), 256, 0, stream>>>(simsb, c1w, c1b, c2w, c2b, feat);

    hipMemsetAsync(hacc, 0, (size_t)NB * 512 * sizeof(float), stream);
    lin_kernel<<<dim3(16, 8, 8), 256, 0, stream>>>(feat, lw, hacc);
    score_kernel<<<NB, 256, 0, stream>>>(hacc, lb, sw, sb, outf);
}

// Round 6
// 960.918 us; speedup vs baseline: 3.4817x; 1.3405x over previous
//
#include <hip/hip_runtime.h>

constexpr int NB = 1024;   // graphs
constexpr int NN = 64;     // nodes per graph
constexpr int ND = 128;    // feature dim (D == G == 128)
constexpr int NE = 512;    // edges per graph
constexpr int FEAT_F = 12288;  // 3*16*16*16

typedef __attribute__((ext_vector_type(8))) short short8v;   // 8 bf16 (4 VGPRs)
typedef __attribute__((ext_vector_type(4))) float f32x4;

__device__ inline ushort f2bf(float x) {                      // fp32 -> bf16 RNE
    unsigned u = __float_as_uint(x);
    u += 0x7FFFu + ((u >> 16) & 1u);
    return (ushort)(u >> 16);
}

// ---------------- build normalized adjacency Â per (graph, side) ----------------
__global__ __launch_bounds__(256)
void adj_kernel(const int* __restrict__ esq, const int* __restrict__ edq,
                const int* __restrict__ esc, const int* __restrict__ edc,
                float* __restrict__ Aq, float* __restrict__ Ac)
{
    __shared__ float A[NN * NN];
    __shared__ float dis[NN];
    const int b = blockIdx.x, side = blockIdx.y, tid = threadIdx.x;
    const int* es = side ? esc : esq;
    const int* ed = side ? edc : edq;
    float* Aout = side ? Ac : Aq;

    for (int i = tid; i < NN * NN; i += 256) A[i] = 0.f;
    __syncthreads();
    for (int e = tid; e < NE; e += 256) {
        const int s = es[b * NE + e] & (NN - 1);
        const int d = ed[b * NE + e] & (NN - 1);
        atomicAdd(&A[d * NN + s], 1.0f);
    }
    __syncthreads();
    if (tid < NN) {
        float sum = 1.0f;                       // self loop
        for (int s = 0; s < NN; s++) sum += A[tid * NN + s];
        dis[tid] = rsqrtf(sum);
    }
    __syncthreads();
    for (int i = tid; i < NN * NN; i += 256) {
        const int d = i >> 6, s = i & 63;
        float v = A[i];
        if (d == s) v += 1.0f;                  // self loop
        Aout[(size_t)b * (NN * NN) + i] = dis[d] * v * dis[s];
    }
}

// ---------------- fused GCN layer: out = Â @ (relu?(H) @ W) + b, both sides ----------------
__global__ __launch_bounds__(512)
void gcn_kernel(const float* __restrict__ hq, const float* __restrict__ hc,
                const float* __restrict__ Aq, const float* __restrict__ Ac,
                const float* __restrict__ W, const float* __restrict__ bias,
                float* __restrict__ outq, float* __restrict__ outc, int relu_in)
{
    __shared__ float w_s[ND * ND];     // 64KB
    __shared__ float h_s[NN * ND];     // 32KB
    __shared__ float m_s[NN * ND];     // 32KB
    __shared__ float a_s[NN * NN];     // 16KB   -> 144KB total, 1 block/CU

    const int b = blockIdx.x, side = blockIdx.y, tid = threadIdx.x;
    const float* h_in = side ? hc : hq;
    const float* A = side ? Ac : Aq;
    float* outp = side ? outc : outq;

    for (int i = tid; i < ND * ND; i += 512) w_s[i] = W[i];
    for (int i = tid; i < NN * ND; i += 512) {
        const float v = h_in[(size_t)b * (NN * ND) + i];
        h_s[i] = relu_in ? fmaxf(v, 0.f) : v;
    }
    for (int i = tid; i < NN * NN; i += 512)
        a_s[i] = A[(size_t)b * (NN * NN) + i];
    __syncthreads();

    const int rg = tid >> 5;            // 0..15 -> rows rg*4..rg*4+3
    const int jc = (tid & 31) * 4;      // cols jc..jc+3

    // M = H @ W
    float acc[4][4];
    #pragma unroll
    for (int ii = 0; ii < 4; ii++)
        #pragma unroll
        for (int jj = 0; jj < 4; jj++) acc[ii][jj] = 0.f;
    for (int k4 = 0; k4 < ND / 4; k4++) {
        float4 wv[4];
        #pragma unroll
        for (int kk = 0; kk < 4; kk++)
            wv[kk] = *(const float4*)&w_s[(k4 * 4 + kk) * ND + jc];
        #pragma unroll
        for (int ii = 0; ii < 4; ii++) {
            const float4 hv = *(const float4*)&h_s[(rg * 4 + ii) * ND + k4 * 4];
            acc[ii][0] += hv.x * wv[0].x + hv.y * wv[1].x + hv.z * wv[2].x + hv.w * wv[3].x;
            acc[ii][1] += hv.x * wv[0].y + hv.y * wv[1].y + hv.z * wv[2].y + hv.w * wv[3].y;
            acc[ii][2] += hv.x * wv[0].z + hv.y * wv[1].z + hv.z * wv[2].z + hv.w * wv[3].z;
            acc[ii][3] += hv.x * wv[0].w + hv.y * wv[1].w + hv.z * wv[2].w + hv.w * wv[3].w;
        }
    }
    #pragma unroll
    for (int ii = 0; ii < 4; ii++)
        *(float4*)&m_s[(rg * 4 + ii) * ND + jc] =
            make_float4(acc[ii][0], acc[ii][1], acc[ii][2], acc[ii][3]);
    __syncthreads();

    // out = Â @ M + bias
    float acc2[4][4];
    #pragma unroll
    for (int ii = 0; ii < 4; ii++)
        #pragma unroll
        for (int jj = 0; jj < 4; jj++) acc2[ii][jj] = 0.f;
    for (int k4 = 0; k4 < NN / 4; k4++) {
        float4 mv[4];
        #pragma unroll
        for (int kk = 0; kk < 4; kk++)
            mv[kk] = *(const float4*)&m_s[(k4 * 4 + kk) * ND + jc];
        #pragma unroll
        for (int ii = 0; ii < 4; ii++) {
            const float4 av = *(const float4*)&a_s[(rg * 4 + ii) * NN + k4 * 4];
            acc2[ii][0] += av.x * mv[0].x + av.y * mv[1].x + av.z * mv[2].x + av.w * mv[3].x;
            acc2[ii][1] += av.x * mv[0].y + av.y * mv[1].y + av.z * mv[2].y + av.w * mv[3].y;
            acc2[ii][2] += av.x * mv[0].z + av.y * mv[1].z + av.z * mv[2].z + av.w * mv[3].z;
            acc2[ii][3] += av.x * mv[0].w + av.y * mv[1].w + av.z * mv[2].w + av.w * mv[3].w;
        }
    }
    const float4 bv = *(const float4*)&bias[jc];
    #pragma unroll
    for (int ii = 0; ii < 4; ii++) {
        float4 o = make_float4(acc2[ii][0] + bv.x, acc2[ii][1] + bv.y,
                               acc2[ii][2] + bv.z, acc2[ii][3] + bv.w);
        *(float4*)&outp[(size_t)b * (NN * ND) + (rg * 4 + ii) * ND + jc] = o;
    }
}

// ---------------- per-graph similarity: S = Q (64x128) x C^T ----------------
__global__ __launch_bounds__(256)
void sims_kernel(const float* __restrict__ fq, const float* __restrict__ fc,
                 float* __restrict__ S)
{
    __shared__ float q_s[64 * 132];
    __shared__ float c_s[64 * 132];
    const int b = blockIdx.x, tid = threadIdx.x;
    for (int i = tid; i < NN * ND; i += 256) {
        const int r = i >> 7, k = i & 127;
        q_s[r * 132 + k] = fq[(size_t)b * (NN * ND) + i];
        c_s[r * 132 + k] = fc[(size_t)b * (NN * ND) + i];
    }
    __syncthreads();
    const int j = tid & 63, ig = tid >> 6;     // ig 0..3
    float acc[16];
    #pragma unroll
    for (int ii = 0; ii < 16; ii++) acc[ii] = 0.f;
    for (int k4 = 0; k4 < 32; k4++) {
        const float4 cv = *(const float4*)&c_s[j * 132 + k4 * 4];
        #pragma unroll
        for (int ii = 0; ii < 16; ii++) {
            const float4 qv = *(const float4*)&q_s[(ig * 16 + ii) * 132 + k4 * 4];
            acc[ii] += qv.x * cv.x + qv.y * cv.y + qv.z * cv.z + qv.w * cv.w;
        }
    }
    for (int ii = 0; ii < 16; ii++)
        S[(size_t)b * 4096 + (ig * 16 + ii) * 64 + j] = acc[ii];
}

// ---------------- fused conv1+relu+pool + conv2+relu+pool ----------------
__global__ __launch_bounds__(256)
void conv_kernel(const float* __restrict__ simsb,
                 const float* __restrict__ c1w, const float* __restrict__ c1b,
                 const float* __restrict__ c2w, const float* __restrict__ c2b,
                 float* __restrict__ feat)
{
    __shared__ float img[68 * 68];       // 64x64 padded by 2
    __shared__ float p1[8 * 36 * 36];    // 8x32x32 padded by 2
    __shared__ float w1s[8 * 25];
    __shared__ float b1s[8];
    __shared__ float w2s[16 * 8 * 28];   // rows padded to 28 for alignment
    __shared__ float b2s[16];

    const int b = blockIdx.x, l = blockIdx.y, tid = threadIdx.x;

    for (int i = tid; i < 68 * 68; i += 256) img[i] = 0.f;
    for (int i = tid; i < 8 * 36 * 36; i += 256) p1[i] = 0.f;
    for (int i = tid; i < 200; i += 256) w1s[i] = c1w[l * 200 + i];
    if (tid < 8)  b1s[tid] = c1b[l * 8 + tid];
    for (int i = tid; i < 16 * 8 * 25; i += 256) {
        const int r = i / 25, cc = i - r * 25;
        w2s[r * 28 + cc] = c2w[l * 3200 + i];
    }
    if (tid < 16) b2s[tid] = c2b[l * 16 + tid];
    __syncthreads();
    for (int i = tid; i < 4096; i += 256) {
        const int y = i >> 6, x = i & 63;
        img[(y + 2) * 68 + (x + 2)] = simsb[((size_t)l * NB + b) * 4096 + i];
    }
    __syncthreads();

    // conv1 (1->8, 5x5, pad2) + relu + 2x2 maxpool
    for (int c = 0; c < 8; c++) {
        float wr[25];
        #pragma unroll
        for (int t = 0; t < 25; t++) wr[t] = w1s[c * 25 + t];
        const float bb = b1s[c];
        #pragma unroll
        for (int q = 0; q < 4; q++) {
            const int o = q * 256 + tid;          // 0..1023
            const int yy = o >> 5, xx = o & 31;
            float patch[36];
            #pragma unroll
            for (int r = 0; r < 6; r++)
                #pragma unroll
                for (int cc = 0; cc < 6; cc++)
                    patch[r * 6 + cc] = img[(2 * yy + r) * 68 + 2 * xx + cc];
            float mval = 0.f;                     // relu floor
            #pragma unroll
            for (int dy = 0; dy < 2; dy++)
                #pragma unroll
                for (int dx = 0; dx < 2; dx++) {
                    float a = bb;
                    #pragma unroll
                    for (int ky = 0; ky < 5; ky++)
                        #pragma unroll
                        for (int kx = 0; kx < 5; kx++)
                            a += patch[(dy + ky) * 6 + dx + kx] * wr[ky * 5 + kx];
                    mval = fmaxf(mval, a);
                }
            p1[c * 1296 + (yy + 2) * 36 + (xx + 2)] = mval;
        }
    }
    __syncthreads();

    // conv2 (8->16, 5x5, pad2) + relu + 2x2 maxpool, write feat layout
    const int yy = tid >> 4, xx = tid & 15;
    for (int cg = 0; cg < 4; cg++) {
        float acc[4][4];
        #pragma unroll
        for (int c4 = 0; c4 < 4; c4++) {
            const float bb = b2s[cg * 4 + c4];
            #pragma unroll
            for (int p = 0; p < 4; p++) acc[c4][p] = bb;
        }
        for (int ci = 0; ci < 8; ci++) {
            float patch[36];
            #pragma unroll
            for (int r = 0; r < 6; r++)
                #pragma unroll
                for (int cc = 0; cc < 6; cc++)
                    patch[r * 6 + cc] = p1[ci * 1296 + (2 * yy + r) * 36 + 2 * xx + cc];
            #pragma unroll
            for (int c4 = 0; c4 < 4; c4++) {
                const float* wp = &w2s[((cg * 4 + c4) * 8 + ci) * 28];
                float wr[25];
                #pragma unroll
                for (int t = 0; t < 25; t++) wr[t] = wp[t];
                #pragma unroll
                for (int dy = 0; dy < 2; dy++)
                    #pragma unroll
                    for (int dx = 0; dx < 2; dx++) {
                        const int p = dy * 2 + dx;
                        #pragma unroll
                        for (int ky = 0; ky < 5; ky++)
                            #pragma unroll
                            for (int kx = 0; kx < 5; kx++)
                                acc[c4][p] += patch[(dy + ky) * 6 + dx + kx] * wr[ky * 5 + kx];
                    }
            }
        }
        #pragma unroll
        for (int c4 = 0; c4 < 4; c4++) {
            float m = 0.f;
            #pragma unroll
            for (int p = 0; p < 4; p++) m = fmaxf(m, acc[c4][p]);
            const int c = cg * 4 + c4;
            feat[(size_t)b * FEAT_F + (((size_t)l * 16 + c) * 16 + yy) * 16 + xx] = m;
        }
    }
}

// ---------------- cast feat fp32 -> bf16 row-major ----------------
__global__ __launch_bounds__(256)
void cast_feat_kernel(const float* __restrict__ in, ushort* __restrict__ o)
{
    const size_t i = ((size_t)blockIdx.x * 256 + threadIdx.x) * 4;  // grid covers exactly
    float4 v = *(const float4*)&in[i];
    ushort4 u = make_ushort4(f2bf(v.x), f2bf(v.y), f2bf(v.z), f2bf(v.w));
    *(ushort4*)&o[i] = u;
}

// ---------------- cast + transpose lw (12288x512) -> lwT bf16 (512x12288) ----------------
__global__ __launch_bounds__(256)
void cast_lwT_kernel(const float* __restrict__ lw, ushort* __restrict__ lwT)
{
    __shared__ ushort t[32][34];
    const int kb = blockIdx.x * 32, nb2 = blockIdx.y * 32;
    const int x = threadIdx.x & 31, y = threadIdx.x >> 5;   // y 0..7
    #pragma unroll
    for (int j = 0; j < 4; j++) {
        const int yy = y + 8 * j;                           // k-local
        t[x][yy] = f2bf(lw[(size_t)(kb + yy) * 512 + nb2 + x]);
    }
    __syncthreads();
    #pragma unroll
    for (int j = 0; j < 4; j++) {
        const int yy = y + 8 * j;                           // n-local
        lwT[(size_t)(nb2 + yy) * FEAT_F + kb + x] = t[yy][x];
    }
}

// ---------------- linear via MFMA: hacc8[kz] = feat_tile @ lw_tile ----------------
// grid (n-tiles=8, m-tiles=16, kz=8); block 256 = 4 waves (2x2), 32x32 out/wave.
__global__ __launch_bounds__(256)
void lin_mfma_kernel(const ushort* __restrict__ featb, const ushort* __restrict__ lwT,
                     float* __restrict__ hacc8)
{
    __shared__ ushort a_s[64][40];     // row-major [m][k], pad 40 for 16B align + banks
    __shared__ ushort b_s[64][40];     // [n][k]
    const int nb = blockIdx.x, mb = blockIdx.y, kz = blockIdx.z;
    const int tid = threadIdx.x;
    const int wid = tid >> 6, lane = tid & 63;
    const int wm = wid >> 1, wn = wid & 1;
    const int m0 = mb * 64, n0 = nb * 64;
    const size_t k0 = (size_t)kz * 1536;

    const int sr = tid >> 2;            // staging row 0..63
    const int sk = (tid & 3) * 8;       // staging k offset 0,8,16,24
    const int kf = (lane >> 4) * 8;     // fragment k offset within 32
    const int rf = lane & 15;           // fragment row/col

    f32x4 zero = {0.f, 0.f, 0.f, 0.f};
    f32x4 acc00 = zero, acc01 = zero, acc10 = zero, acc11 = zero;

    for (int ks = 0; ks < 48; ks++) {
        const size_t kc = k0 + (size_t)ks * 32;
        *(short8v*)&a_s[sr][sk] = *(const short8v*)&featb[(size_t)(m0 + sr) * FEAT_F + kc + sk];
        *(short8v*)&b_s[sr][sk] = *(const short8v*)&lwT[(size_t)(n0 + sr) * FEAT_F + kc + sk];
        __syncthreads();
        short8v af0 = *(const short8v*)&a_s[wm * 32 + rf][kf];
        short8v af1 = *(const short8v*)&a_s[wm * 32 + 16 + rf][kf];
        short8v bf0 = *(const short8v*)&b_s[wn * 32 + rf][kf];
        short8v bf1 = *(const short8v*)&b_s[wn * 32 + 16 + rf][kf];
        acc00 = __builtin_amdgcn_mfma_f32_16x16x32_bf16(af0, bf0, acc00, 0, 0, 0);
        acc01 = __builtin_amdgcn_mfma_f32_16x16x32_bf16(af0, bf1, acc01, 0, 0, 0);
        acc10 = __builtin_amdgcn_mfma_f32_16x16x32_bf16(af1, bf0, acc10, 0, 0, 0);
        acc11 = __builtin_amdgcn_mfma_f32_16x16x32_bf16(af1, bf1, acc11, 0, 0, 0);
        __syncthreads();
    }
    // C/D layout: col = lane&15, row = (lane>>4)*4 + reg  [guide-verified]
    float* outz = hacc8 + (size_t)kz * 1024 * 512;
    const int rbase = m0 + wm * 32 + (lane >> 4) * 4;
    const int cbase = n0 + wn * 32 + rf;
    #pragma unroll
    for (int r = 0; r < 4; r++) {
        outz[(size_t)(rbase + r) * 512 + cbase]           = acc00[r];
        outz[(size_t)(rbase + r) * 512 + cbase + 16]      = acc01[r];
        outz[(size_t)(rbase + 16 + r) * 512 + cbase]      = acc10[r];
        outz[(size_t)(rbase + 16 + r) * 512 + cbase + 16] = acc11[r];
    }
}

// ---------------- sum split-K + bias + relu + score dot ----------------
__global__ __launch_bounds__(256)
void score_kernel(const float* __restrict__ hacc8, const float* __restrict__ lb,
                  const float* __restrict__ sw, const float* __restrict__ sb,
                  float* __restrict__ outp)
{
    const int b = blockIdx.x, tid = threadIdx.x;
    float v = 0.f;
    for (int j = tid; j < 512; j += 256) {
        float s = lb[j];
        #pragma unroll
        for (int z = 0; z < 8; z++)
            s += hacc8[((size_t)z * 1024 + b) * 512 + j];
        v += fmaxf(s, 0.f) * sw[j];
    }
    #pragma unroll
    for (int off = 32; off > 0; off >>= 1) v += __shfl_down(v, off);
    __shared__ float red[4];
    if ((tid & 63) == 0) red[tid >> 6] = v;
    __syncthreads();
    if (tid == 0) outp[b] = red[0] + red[1] + red[2] + red[3] + sb[0];
}

extern "C" void kernel_launch(void* const* d_in, const int* in_sizes, int n_in,
                              void* d_out, int out_size, void* d_ws, size_t ws_size,
                              hipStream_t stream)
{
    const float* x_q = (const float*)d_in[0];
    const float* x_c = (const float*)d_in[1];
    const float* gw[3] = {(const float*)d_in[2], (const float*)d_in[4], (const float*)d_in[6]};
    const float* gb[3] = {(const float*)d_in[3], (const float*)d_in[5], (const float*)d_in[7]};
    const float* c1w = (const float*)d_in[8];
    const float* c1b = (const float*)d_in[9];
    const float* c2w = (const float*)d_in[10];
    const float* c2b = (const float*)d_in[11];
    const float* lw  = (const float*)d_in[12];
    const float* lb  = (const float*)d_in[13];
    const float* sw  = (const float*)d_in[14];
    const float* sb  = (const float*)d_in[15];
    const int* eq = (const int*)d_in[16];
    const int* ec = (const int*)d_in[17];

    // Workspace (floats). Distinct = 58,720,256 fl = 224 MiB (< ~256 MiB cap).
    // Liveness aliases: feat -> q1(+c1 head) [q1,c1 dead after gcn3];
    // featb -> q0, lwT -> c0 [q0,c0 dead after sims3].
    float* ws = (float*)d_ws;
    float* q0 = ws;                                        // 8.39M fl
    float* c0 = q0 + (size_t)NB * NN * ND;                 // 8.39M
    float* q1 = c0 + (size_t)NB * NN * ND;                 // 8.39M } contiguous
    float* c1 = q1 + (size_t)NB * NN * ND;                 // 8.39M } 16.78M
    float* simsb = c1 + (size_t)NB * NN * ND;              // 12.58M (3*NB*4096)
    float* hacc8 = simsb + (size_t)3 * NB * NN * NN;       // 8*1024*512 = 4.19M
    float* Aq    = hacc8 + (size_t)8 * NB * 512;           // 4.19M
    float* Ac    = Aq + (size_t)NB * NN * NN;              // 4.19M
    float* feat  = q1;                                     // alias, 12.58M of 16.78M
    ushort* featb = (ushort*)q0;                           // alias, 12.58M us = 6.29M fl
    ushort* lwT   = (ushort*)c0;                           // alias, 6.29M us = 3.15M fl
    float* outf = (float*)d_out;

    const int* esq = eq;
    const int* edq = eq + (size_t)NB * NE;
    const int* esc = ec;
    const int* edc = ec + (size_t)NB * NE;

    adj_kernel<<<dim3(NB, 2), 256, 0, stream>>>(esq, edq, esc, edc, Aq, Ac);

    gcn_kernel<<<dim3(NB, 2), 512, 0, stream>>>(x_q, x_c, Aq, Ac, gw[0], gb[0], q0, c0, 0);
    sims_kernel<<<NB, 256, 0, stream>>>(q0, c0, simsb);
    gcn_kernel<<<dim3(NB, 2), 512, 0, stream>>>(q0, c0, Aq, Ac, gw[1], gb[1], q1, c1, 1);
    sims_kernel<<<NB, 256, 0, stream>>>(q1, c1, simsb + (size_t)NB * NN * NN);
    gcn_kernel<<<dim3(NB, 2), 512, 0, stream>>>(q1, c1, Aq, Ac, gw[2], gb[2], q0, c0, 1);
    sims_kernel<<<NB, 256, 0, stream>>>(q0, c0, simsb + (size_t)2 * NB * NN * NN);

    conv_kernel<<<dim3(NB, 3), 256, 0, stream>>>(simsb, c1w, c1b, c2w, c2b, feat);

    // casts (q0/c0 dead now), then MFMA GEMM, then score
    cast_feat_kernel<<<(NB * FEAT_F) / 1024, 256, 0, stream>>>(feat, featb);
    cast_lwT_kernel<<<dim3(FEAT_F / 32, 512 / 32), 256, 0, stream>>>(lw, lwT);
    lin_mfma_kernel<<<dim3(8, 16, 8), 256, 0, stream>>>(featb, lwT, hacc8);
    score_kernel<<<NB, 256, 0, stream>>>(hacc8, lb, sw, sb, outf);
}

// Round 8
// 720.055 us; speedup vs baseline: 4.6463x; 1.3345x over previous
//
#include <hip/hip_runtime.h>

constexpr int NB = 1024;   // graphs
constexpr int NN = 64;     // nodes per graph
constexpr int ND = 128;    // feature dim (D == G == 128)
constexpr int NE = 512;    // edges per graph
constexpr int FEAT_F = 12288;  // 3*16*16*16

typedef __attribute__((ext_vector_type(8))) short short8v;   // 8 bf16 (4 VGPRs)
typedef __attribute__((ext_vector_type(4))) float f32x4;

__device__ inline ushort f2bf(float x) {                      // fp32 -> bf16 RNE
    unsigned u = __float_as_uint(x);
    u += 0x7FFFu + ((u >> 16) & 1u);
    return (ushort)(u >> 16);
}

// ---------------- build normalized adjacency Â per (graph, side) ----------------
__global__ __launch_bounds__(256)
void adj_kernel(const int* __restrict__ esq, const int* __restrict__ edq,
                const int* __restrict__ esc, const int* __restrict__ edc,
                float* __restrict__ Aq, float* __restrict__ Ac)
{
    __shared__ float A[NN * NN];
    __shared__ float dis[NN];
    const int b = blockIdx.x, side = blockIdx.y, tid = threadIdx.x;
    const int* es = side ? esc : esq;
    const int* ed = side ? edc : edq;
    float* Aout = side ? Ac : Aq;

    for (int i = tid; i < NN * NN; i += 256) A[i] = 0.f;
    __syncthreads();
    for (int e = tid; e < NE; e += 256) {
        const int s = es[b * NE + e] & (NN - 1);
        const int d = ed[b * NE + e] & (NN - 1);
        atomicAdd(&A[d * NN + s], 1.0f);
    }
    __syncthreads();
    if (tid < NN) {
        float sum = 1.0f;                       // self loop
        for (int s = 0; s < NN; s++) sum += A[tid * NN + s];
        dis[tid] = rsqrtf(sum);
    }
    __syncthreads();
    for (int i = tid; i < NN * NN; i += 256) {
        const int d = i >> 6, s = i & 63;
        float v = A[i];
        if (d == s) v += 1.0f;                  // self loop
        Aout[(size_t)b * (NN * NN) + i] = dis[d] * v * dis[s];
    }
}

// ---------------- fused GCN layer: out = Â @ (relu?(H) @ W) + b, both sides ----------------
__global__ __launch_bounds__(512)
void gcn_kernel(const float* __restrict__ hq, const float* __restrict__ hc,
                const float* __restrict__ Aq, const float* __restrict__ Ac,
                const float* __restrict__ W, const float* __restrict__ bias,
                float* __restrict__ outq, float* __restrict__ outc, int relu_in)
{
    __shared__ float w_s[ND * ND];     // 64KB
    __shared__ float h_s[NN * ND];     // 32KB
    __shared__ float m_s[NN * ND];     // 32KB
    __shared__ float a_s[NN * NN];     // 16KB   -> 144KB total, 1 block/CU

    const int b = blockIdx.x, side = blockIdx.y, tid = threadIdx.x;
    const float* h_in = side ? hc : hq;
    const float* A = side ? Ac : Aq;
    float* outp = side ? outc : outq;

    for (int i = tid; i < ND * ND; i += 512) w_s[i] = W[i];
    for (int i = tid; i < NN * ND; i += 512) {
        const float v = h_in[(size_t)b * (NN * ND) + i];
        h_s[i] = relu_in ? fmaxf(v, 0.f) : v;
    }
    for (int i = tid; i < NN * NN; i += 512)
        a_s[i] = A[(size_t)b * (NN * NN) + i];
    __syncthreads();

    const int rg = tid >> 5;            // 0..15 -> rows rg*4..rg*4+3
    const int jc = (tid & 31) * 4;      // cols jc..jc+3

    // M = H @ W
    float acc[4][4];
    #pragma unroll
    for (int ii = 0; ii < 4; ii++)
        #pragma unroll
        for (int jj = 0; jj < 4; jj++) acc[ii][jj] = 0.f;
    for (int k4 = 0; k4 < ND / 4; k4++) {
        float4 wv[4];
        #pragma unroll
        for (int kk = 0; kk < 4; kk++)
            wv[kk] = *(const float4*)&w_s[(k4 * 4 + kk) * ND + jc];
        #pragma unroll
        for (int ii = 0; ii < 4; ii++) {
            const float4 hv = *(const float4*)&h_s[(rg * 4 + ii) * ND + k4 * 4];
            acc[ii][0] += hv.x * wv[0].x + hv.y * wv[1].x + hv.z * wv[2].x + hv.w * wv[3].x;
            acc[ii][1] += hv.x * wv[0].y + hv.y * wv[1].y + hv.z * wv[2].y + hv.w * wv[3].y;
            acc[ii][2] += hv.x * wv[0].z + hv.y * wv[1].z + hv.z * wv[2].z + hv.w * wv[3].z;
            acc[ii][3] += hv.x * wv[0].w + hv.y * wv[1].w + hv.z * wv[2].w + hv.w * wv[3].w;
        }
    }
    #pragma unroll
    for (int ii = 0; ii < 4; ii++)
        *(float4*)&m_s[(rg * 4 + ii) * ND + jc] =
            make_float4(acc[ii][0], acc[ii][1], acc[ii][2], acc[ii][3]);
    __syncthreads();

    // out = Â @ M + bias
    float acc2[4][4];
    #pragma unroll
    for (int ii = 0; ii < 4; ii++)
        #pragma unroll
        for (int jj = 0; jj < 4; jj++) acc2[ii][jj] = 0.f;
    for (int k4 = 0; k4 < NN / 4; k4++) {
        float4 mv[4];
        #pragma unroll
        for (int kk = 0; kk < 4; kk++)
            mv[kk] = *(const float4*)&m_s[(k4 * 4 + kk) * ND + jc];
        #pragma unroll
        for (int ii = 0; ii < 4; ii++) {
            const float4 av = *(const float4*)&a_s[(rg * 4 + ii) * NN + k4 * 4];
            acc2[ii][0] += av.x * mv[0].x + av.y * mv[1].x + av.z * mv[2].x + av.w * mv[3].x;
            acc2[ii][1] += av.x * mv[0].y + av.y * mv[1].y + av.z * mv[2].y + av.w * mv[3].y;
            acc2[ii][2] += av.x * mv[0].z + av.y * mv[1].z + av.z * mv[2].z + av.w * mv[3].z;
            acc2[ii][3] += av.x * mv[0].w + av.y * mv[1].w + av.z * mv[2].w + av.w * mv[3].w;
        }
    }
    const float4 bv = *(const float4*)&bias[jc];
    #pragma unroll
    for (int ii = 0; ii < 4; ii++) {
        float4 o = make_float4(acc2[ii][0] + bv.x, acc2[ii][1] + bv.y,
                               acc2[ii][2] + bv.z, acc2[ii][3] + bv.w);
        *(float4*)&outp[(size_t)b * (NN * ND) + (rg * 4 + ii) * ND + jc] = o;
    }
}

// ---------------- per-graph similarity: S = Q (64x128) x C^T ----------------
__global__ __launch_bounds__(256)
void sims_kernel(const float* __restrict__ fq, const float* __restrict__ fc,
                 float* __restrict__ S)
{
    __shared__ float q_s[64 * 132];
    __shared__ float c_s[64 * 132];
    const int b = blockIdx.x, tid = threadIdx.x;
    for (int i = tid; i < NN * ND; i += 256) {
        const int r = i >> 7, k = i & 127;
        q_s[r * 132 + k] = fq[(size_t)b * (NN * ND) + i];
        c_s[r * 132 + k] = fc[(size_t)b * (NN * ND) + i];
    }
    __syncthreads();
    const int j = tid & 63, ig = tid >> 6;     // ig 0..3
    float acc[16];
    #pragma unroll
    for (int ii = 0; ii < 16; ii++) acc[ii] = 0.f;
    for (int k4 = 0; k4 < 32; k4++) {
        const float4 cv = *(const float4*)&c_s[j * 132 + k4 * 4];
        #pragma unroll
        for (int ii = 0; ii < 16; ii++) {
            const float4 qv = *(const float4*)&q_s[(ig * 16 + ii) * 132 + k4 * 4];
            acc[ii] += qv.x * cv.x + qv.y * cv.y + qv.z * cv.z + qv.w * cv.w;
        }
    }
    for (int ii = 0; ii < 16; ii++)
        S[(size_t)b * 4096 + (ig * 16 + ii) * 64 + j] = acc[ii];
}

// ---------------- conv1 (fp32, reg-blocked) + conv2 (bf16 implicit-GEMM MFMA) ----------------
// Per (b,l): conv1+relu+pool -> p1b bf16 [36y][36x][8cin] (pad 2, zero borders);
// conv2 as GEMM M=x-positions, N=16 couts, K=200->224 (28 taps x 8 cin, taps>=25 zero
// via reading the all-zero pad row 35); relu+pool in registers; write featb bf16.
__global__ __launch_bounds__(256)
void conv_kernel(const float* __restrict__ simsb,
                 const float* __restrict__ c1w, const float* __restrict__ c1b,
                 const float* __restrict__ c2w, const float* __restrict__ c2b,
                 ushort* __restrict__ featb)
{
    __shared__ float img[68 * 68];          // 18.5KB, 64x64 padded by 2
    __shared__ ushort p1b[36 * 36 * 8];     // 20.7KB
    __shared__ ushort w2s[16][232];         // 7.4KB, [cout][k=tap*8+cin], pad->232 (2-way banks)

    const int b = blockIdx.x, l = blockIdx.y, tid = threadIdx.x;
    const int lane = tid & 63, wid = tid >> 6;
    const int q = lane >> 4, rf = lane & 15;

    for (int i = tid; i < 68 * 68; i += 256) img[i] = 0.f;
    for (int i = tid; i < 36 * 36 * 8 / 2; i += 256) ((uint*)p1b)[i] = 0u;
    for (int i = tid; i < 16 * 224; i += 256) {
        const int co = i / 224, k = i - co * 224;
        const int tap = k >> 3, ci = k & 7;
        w2s[co][k] = (tap < 25) ? f2bf(c2w[l * 3200 + co * 200 + ci * 25 + tap])
                                : (ushort)0;
    }
    __syncthreads();
    for (int i = tid; i < 4096; i += 256) {
        const int y = i >> 6, x = i & 63;
        img[(y + 2) * 68 + (x + 2)] = simsb[((size_t)l * NB + b) * 4096 + i];
    }
    __syncthreads();

    // ---- conv1: thread owns 4x4 pre-pool block at (4by, 4bx); patch 8x8 in regs ----
    {
        const int by = tid >> 4, bx = tid & 15;
        float pt[8][8];
        #pragma unroll
        for (int r = 0; r < 8; r++)
            #pragma unroll
            for (int c2 = 0; c2 < 4; c2++) {
                const float2 v = *(const float2*)&img[(4 * by + r) * 68 + 4 * bx + 2 * c2];
                pt[r][2 * c2] = v.x; pt[r][2 * c2 + 1] = v.y;
            }
        for (int c = 0; c < 8; c++) {
            float wr[25];                          // wave-uniform -> s_loads
            #pragma unroll
            for (int t = 0; t < 25; t++) wr[t] = c1w[l * 200 + c * 25 + t];
            const float bb = c1b[l * 8 + c];
            #pragma unroll
            for (int jy = 0; jy < 2; jy++)
                #pragma unroll
                for (int jx = 0; jx < 2; jx++) {
                    float m = 0.f;                 // relu floor
                    #pragma unroll
                    for (int dy = 0; dy < 2; dy++)
                        #pragma unroll
                        for (int dx = 0; dx < 2; dx++) {
                            float a = bb;
                            #pragma unroll
                            for (int ky = 0; ky < 5; ky++)
                                #pragma unroll
                                for (int kx = 0; kx < 5; kx++)
                                    a += pt[2 * jy + dy + ky][2 * jx + dx + kx] * wr[ky * 5 + kx];
                            m = fmaxf(m, a);
                        }
                    p1b[((2 * by + jy + 2) * 36 + (2 * bx + jx + 2)) * 8 + c] = f2bf(m);
                }
        }
    }
    __syncthreads();

    // ---- conv2 MFMA: wave handles y-pairs r = wid+4t; 4 acc chains (2 y x 2 x-halves) ----
    short8v bf[7];
    #pragma unroll
    for (int ks = 0; ks < 7; ks++)
        bf[ks] = *(const short8v*)&w2s[rf][32 * ks + 8 * q];
    const float bb2 = c2b[l * 16 + rf];            // cout = C col = lane&15

    for (int t = 0; t < 4; t++) {
        const int r = wid + 4 * t;                 // pooled y index 0..15
        f32x4 acc00 = {0.f,0.f,0.f,0.f}, acc01 = acc00, acc10 = acc00, acc11 = acc00;
        #pragma unroll
        for (int ks = 0; ks < 7; ks++) {
            const int tap = 4 * ks + q;
            const int dy = tap / 5, dx = tap - 5 * dy;
            const bool dum = tap >= 25;
            const int row0 = dum ? 35 : (2 * r + dy);
            const int row1 = dum ? 35 : (2 * r + 1 + dy);
            const int cb   = (dum ? 0 : dx) + rf;
            const short8v a00 = *(const short8v*)&p1b[(row0 * 36 + cb) * 8];
            const short8v a01 = *(const short8v*)&p1b[(row0 * 36 + cb + 16) * 8];
            const short8v a10 = *(const short8v*)&p1b[(row1 * 36 + cb) * 8];
            const short8v a11 = *(const short8v*)&p1b[(row1 * 36 + cb + 16) * 8];
            acc00 = __builtin_amdgcn_mfma_f32_16x16x32_bf16(a00, bf[ks], acc00, 0, 0, 0);
            acc01 = __builtin_amdgcn_mfma_f32_16x16x32_bf16(a01, bf[ks], acc01, 0, 0, 0);
            acc10 = __builtin_amdgcn_mfma_f32_16x16x32_bf16(a10, bf[ks], acc10, 0, 0, 0);
            acc11 = __builtin_amdgcn_mfma_f32_16x16x32_bf16(a11, bf[ks], acc11, 0, 0, 0);
        }
        // pool over y (acc0x vs acc1x) and x reg-pairs; bias; relu; write bf16
        const float v0 = fmaxf(fmaxf(fmaxf(acc00[0], acc00[1]), fmaxf(acc10[0], acc10[1])) + bb2, 0.f);
        const float v1 = fmaxf(fmaxf(fmaxf(acc00[2], acc00[3]), fmaxf(acc10[2], acc10[3])) + bb2, 0.f);
        const float v2 = fmaxf(fmaxf(fmaxf(acc01[0], acc01[1]), fmaxf(acc11[0], acc11[1])) + bb2, 0.f);
        const float v3 = fmaxf(fmaxf(fmaxf(acc01[2], acc01[3]), fmaxf(acc11[2], acc11[3])) + bb2, 0.f);
        const size_t base = (size_t)b * FEAT_F + ((size_t)l * 16 + rf) * 256 + r * 16;
        featb[base + 2 * q]         = f2bf(v0);
        featb[base + 2 * q + 1]     = f2bf(v1);
        featb[base + 8 + 2 * q]     = f2bf(v2);
        featb[base + 8 + 2 * q + 1] = f2bf(v3);
    }
}

// ---------------- cast + transpose lw (12288x512) -> lwT bf16 (512x12288) ----------------
__global__ __launch_bounds__(256)
void cast_lwT_kernel(const float* __restrict__ lw, ushort* __restrict__ lwT)
{
    __shared__ ushort t[32][34];
    const int kb = blockIdx.x * 32, nb2 = blockIdx.y * 32;
    const int x = threadIdx.x & 31, y = threadIdx.x >> 5;   // y 0..7
    #pragma unroll
    for (int j = 0; j < 4; j++) {
        const int yy = y + 8 * j;                           // k-local
        t[x][yy] = f2bf(lw[(size_t)(kb + yy) * 512 + nb2 + x]);
    }
    __syncthreads();
    #pragma unroll
    for (int j = 0; j < 4; j++) {
        const int yy = y + 8 * j;                           // n-local
        lwT[(size_t)(nb2 + yy) * FEAT_F + kb + x] = t[yy][x];
    }
}

// ---------------- linear via MFMA: hacc8[kz] = feat_tile @ lw_tile ----------------
// grid (n-tiles=8, m-tiles=16, kz=8); block 256 = 4 waves (2x2), 32x32 out/wave.
__global__ __launch_bounds__(256)
void lin_mfma_kernel(const ushort* __restrict__ featb, const ushort* __restrict__ lwT,
                     float* __restrict__ hacc8)
{
    __shared__ ushort a_s[64][40];     // row-major [m][k], pad 40 for 16B align + banks
    __shared__ ushort b_s[64][40];     // [n][k]
    const int nb = blockIdx.x, mb = blockIdx.y, kz = blockIdx.z;
    const int tid = threadIdx.x;
    const int wid = tid >> 6, lane = tid & 63;
    const int wm = wid >> 1, wn = wid & 1;
    const int m0 = mb * 64, n0 = nb * 64;
    const size_t k0 = (size_t)kz * 1536;

    const int sr = tid >> 2;            // staging row 0..63
    const int sk = (tid & 3) * 8;       // staging k offset 0,8,16,24
    const int kf = (lane >> 4) * 8;     // fragment k offset within 32
    const int rf = lane & 15;           // fragment row/col

    f32x4 zero = {0.f, 0.f, 0.f, 0.f};
    f32x4 acc00 = zero, acc01 = zero, acc10 = zero, acc11 = zero;

    for (int ks = 0; ks < 48; ks++) {
        const size_t kc = k0 + (size_t)ks * 32;
        *(short8v*)&a_s[sr][sk] = *(const short8v*)&featb[(size_t)(m0 + sr) * FEAT_F + kc + sk];
        *(short8v*)&b_s[sr][sk] = *(const short8v*)&lwT[(size_t)(n0 + sr) * FEAT_F + kc + sk];
        __syncthreads();
        short8v af0 = *(const short8v*)&a_s[wm * 32 + rf][kf];
        short8v af1 = *(const short8v*)&a_s[wm * 32 + 16 + rf][kf];
        short8v bf0 = *(const short8v*)&b_s[wn * 32 + rf][kf];
        short8v bf1 = *(const short8v*)&b_s[wn * 32 + 16 + rf][kf];
        acc00 = __builtin_amdgcn_mfma_f32_16x16x32_bf16(af0, bf0, acc00, 0, 0, 0);
        acc01 = __builtin_amdgcn_mfma_f32_16x16x32_bf16(af0, bf1, acc01, 0, 0, 0);
        acc10 = __builtin_amdgcn_mfma_f32_16x16x32_bf16(af1, bf0, acc10, 0, 0, 0);
        acc11 = __builtin_amdgcn_mfma_f32_16x16x32_bf16(af1, bf1, acc11, 0, 0, 0);
        __syncthreads();
    }
    // C/D layout: col = lane&15, row = (lane>>4)*4 + reg  [hw-verified round 6]
    float* outz = hacc8 + (size_t)kz * 1024 * 512;
    const int rbase = m0 + wm * 32 + (lane >> 4) * 4;
    const int cbase = n0 + wn * 32 + rf;
    #pragma unroll
    for (int r = 0; r < 4; r++) {
        outz[(size_t)(rbase + r) * 512 + cbase]           = acc00[r];
        outz[(size_t)(rbase + r) * 512 + cbase + 16]      = acc01[r];
        outz[(size_t)(rbase + 16 + r) * 512 + cbase]      = acc10[r];
        outz[(size_t)(rbase + 16 + r) * 512 + cbase + 16] = acc11[r];
    }
}

// ---------------- sum split-K + bias + relu + score dot ----------------
__global__ __launch_bounds__(256)
void score_kernel(const float* __restrict__ hacc8, const float* __restrict__ lb,
                  const float* __restrict__ sw, const float* __restrict__ sb,
                  float* __restrict__ outp)
{
    const int b = blockIdx.x, tid = threadIdx.x;
    float v = 0.f;
    for (int j = tid; j < 512; j += 256) {
        float s = lb[j];
        #pragma unroll
        for (int z = 0; z < 8; z++)
            s += hacc8[((size_t)z * 1024 + b) * 512 + j];
        v += fmaxf(s, 0.f) * sw[j];
    }
    #pragma unroll
    for (int off = 32; off > 0; off >>= 1) v += __shfl_down(v, off);
    __shared__ float red[4];
    if ((tid & 63) == 0) red[tid >> 6] = v;
    __syncthreads();
    if (tid == 0) outp[b] = red[0] + red[1] + red[2] + red[3] + sb[0];
}

extern "C" void kernel_launch(void* const* d_in, const int* in_sizes, int n_in,
                              void* d_out, int out_size, void* d_ws, size_t ws_size,
                              hipStream_t stream)
{
    const float* x_q = (const float*)d_in[0];
    const float* x_c = (const float*)d_in[1];
    const float* gw[3] = {(const float*)d_in[2], (const float*)d_in[4], (const float*)d_in[6]};
    const float* gb[3] = {(const float*)d_in[3], (const float*)d_in[5], (const float*)d_in[7]};
    const float* c1w = (const float*)d_in[8];
    const float* c1b = (const float*)d_in[9];
    const float* c2w = (const float*)d_in[10];
    const float* c2b = (const float*)d_in[11];
    const float* lw  = (const float*)d_in[12];
    const float* lb  = (const float*)d_in[13];
    const float* sw  = (const float*)d_in[14];
    const float* sb  = (const float*)d_in[15];
    const int* eq = (const int*)d_in[16];
    const int* ec = (const int*)d_in[17];

    // Workspace (floats), 224 MiB distinct (< cap). Liveness aliases:
    // featb -> q1 region (q1 dead after gcn3 launch; conv runs after sims3);
    // lwT -> c0 region (c0 dead after sims3; cast_lwT launches after sims3).
    float* ws = (float*)d_ws;
    float* q0 = ws;                                        // 8.39M fl
    float* c0 = q0 + (size_t)NB * NN * ND;                 // 8.39M
    float* q1 = c0 + (size_t)NB * NN * ND;                 // 8.39M
    float* c1 = q1 + (size_t)NB * NN * ND;                 // 8.39M
    float* simsb = c1 + (size_t)NB * NN * ND;              // 12.58M (3*NB*4096)
    float* hacc8 = simsb + (size_t)3 * NB * NN * NN;       // 8*1024*512 = 4.19M
    float* Aq    = hacc8 + (size_t)8 * NB * 512;           // 4.19M
    float* Ac    = Aq + (size_t)NB * NN * NN;              // 4.19M
    ushort* featb = (ushort*)q1;                           // 25.2MB < q1's 33.5MB
    ushort* lwT   = (ushort*)c0;                           // 12.6MB < c0's 33.5MB
    float* outf = (float*)d_out;

    const int* esq = eq;
    const int* edq = eq + (size_t)NB * NE;
    const int* esc = ec;
    const int* edc = ec + (size_t)NB * NE;

    adj_kernel<<<dim3(NB, 2), 256, 0, stream>>>(esq, edq, esc, edc, Aq, Ac);

    gcn_kernel<<<dim3(NB, 2), 512, 0, stream>>>(x_q, x_c, Aq, Ac, gw[0], gb[0], q0, c0, 0);
    sims_kernel<<<NB, 256, 0, stream>>>(q0, c0, simsb);
    gcn_kernel<<<dim3(NB, 2), 512, 0, stream>>>(q0, c0, Aq, Ac, gw[1], gb[1], q1, c1, 1);
    sims_kernel<<<NB, 256, 0, stream>>>(q1, c1, simsb + (size_t)NB * NN * NN);
    gcn_kernel<<<dim3(NB, 2), 512, 0, stream>>>(q1, c1, Aq, Ac, gw[2], gb[2], q0, c0, 1);
    sims_kernel<<<NB, 256, 0, stream>>>(q0, c0, simsb + (size_t)2 * NB * NN * NN);

    cast_lwT_kernel<<<dim3(FEAT_F / 32, 512 / 32), 256, 0, stream>>>(lw, lwT);
    conv_kernel<<<dim3(NB, 3), 256, 0, stream>>>(simsb, c1w, c1b, c2w, c2b, featb);

    lin_mfma_kernel<<<dim3(8, 16, 8), 256, 0, stream>>>(featb, lwT, hacc8);
    score_kernel<<<NB, 256, 0, stream>>>(hacc8, lb, sw, sb, outf);
}

// Round 9
// 408.712 us; speedup vs baseline: 8.1857x; 1.7618x over previous
//
#include <hip/hip_runtime.h>

constexpr int NB = 1024;   // graphs
constexpr int NN = 64;     // nodes per graph
constexpr int ND = 128;    // feature dim (D == G == 128)
constexpr int NE = 512;    // edges per graph
constexpr int FEAT_F = 12288;  // 3*16*16*16

typedef __attribute__((ext_vector_type(8))) short short8v;   // 8 bf16 (4 VGPRs)
typedef __attribute__((ext_vector_type(4))) float f32x4;

__device__ inline ushort f2bf(float x) {                      // fp32 -> bf16 RNE
    unsigned u = __float_as_uint(x);
    u += 0x7FFFu + ((u >> 16) & 1u);
    return (ushort)(u >> 16);
}

// ---------------- build normalized adjacency Â (bf16) per (graph, side) ----------------
__global__ __launch_bounds__(256)
void adj_kernel(const int* __restrict__ esq, const int* __restrict__ edq,
                const int* __restrict__ esc, const int* __restrict__ edc,
                ushort* __restrict__ Aq, ushort* __restrict__ Ac)
{
    __shared__ float A[NN * NN];
    __shared__ float dis[NN];
    const int b = blockIdx.x, side = blockIdx.y, tid = threadIdx.x;
    const int* es = side ? esc : esq;
    const int* ed = side ? edc : edq;
    ushort* Aout = side ? Ac : Aq;

    for (int i = tid; i < NN * NN; i += 256) A[i] = 0.f;
    __syncthreads();
    for (int e = tid; e < NE; e += 256) {
        const int s = es[b * NE + e] & (NN - 1);
        const int d = ed[b * NE + e] & (NN - 1);
        atomicAdd(&A[d * NN + s], 1.0f);
    }
    __syncthreads();
    if (tid < NN) {
        float sum = 1.0f;                       // self loop
        for (int s = 0; s < NN; s++) sum += A[tid * NN + s];
        dis[tid] = rsqrtf(sum);
    }
    __syncthreads();
    for (int i = tid; i < NN * NN; i += 256) {
        const int d = i >> 6, s = i & 63;
        float v = A[i];
        if (d == s) v += 1.0f;                  // self loop
        Aout[(size_t)b * (NN * NN) + i] = f2bf(dis[d] * v * dis[s]);
    }
}

// ---------------- cast+transpose gcn weights: wtb[l][f][k] = bf16(W_l[k][f]) ----------------
__global__ __launch_bounds__(256)
void castw_kernel(const float* __restrict__ w0, const float* __restrict__ w1,
                  const float* __restrict__ w2, ushort* __restrict__ wtb)
{
    const float* W = blockIdx.x == 0 ? w0 : (blockIdx.x == 1 ? w1 : w2);
    ushort* out = wtb + (size_t)blockIdx.x * ND * ND;
    for (int i = threadIdx.x; i < ND * ND; i += 256) {
        const int f = i >> 7, k = i & 127;
        out[i] = f2bf(W[k * ND + f]);
    }
}

// ---------------- GCN layer via MFMA: out = Â @ (relu?(H) @ W) + b, bf16 ----------------
// block 256 = 4 waves; wave w owns rows 16w..16w+15 of both matmuls.
__global__ __launch_bounds__(256)
void gcn_mfma_kernel(const void* __restrict__ hq_in, const void* __restrict__ hc_in,
                     const ushort* __restrict__ Aqb, const ushort* __restrict__ Acb,
                     const ushort* __restrict__ wt_l, const float* __restrict__ bias,
                     ushort* __restrict__ outq, ushort* __restrict__ outc, int first)
{
    __shared__ ushort ht[64][132];     // H bf16 (relu'd), 16.9KB
    __shared__ ushort wt[128][132];    // W^T [f][k], 33.8KB
    __shared__ ushort mT[128][68];     // M^T [f][s], 17.4KB
    __shared__ ushort as_[64][68];     // Â [d][s], 8.7KB   -> 76.8KB, 2 blocks/CU

    const int b = blockIdx.x, side = blockIdx.y, tid = threadIdx.x;
    const int lane = tid & 63, w = tid >> 6;
    const int q = lane >> 4, rf = lane & 15;

    const ushort* Ab = (side ? Acb : Aqb) + (size_t)b * 4096;
    ushort* outp = (side ? outc : outq) + (size_t)b * 8192;

    // ---- stage ht (64x128): thread -> row tid>>2, 32-elem chunk (tid&3)*32 ----
    {
        const int sr = tid >> 2, sc = (tid & 3) * 32;
        if (first) {
            const float* hin = (const float*)(side ? hc_in : hq_in) + (size_t)b * 8192 + sr * 128 + sc;
            #pragma unroll
            for (int j = 0; j < 4; j++) {
                const float4 v0 = *(const float4*)&hin[8 * j];
                const float4 v1 = *(const float4*)&hin[8 * j + 4];
                *(ushort4*)&ht[sr][sc + 8 * j]     = make_ushort4(f2bf(v0.x), f2bf(v0.y), f2bf(v0.z), f2bf(v0.w));
                *(ushort4*)&ht[sr][sc + 8 * j + 4] = make_ushort4(f2bf(v1.x), f2bf(v1.y), f2bf(v1.z), f2bf(v1.w));
            }
        } else {
            const ushort* hin = (const ushort*)(side ? hc_in : hq_in) + (size_t)b * 8192 + sr * 128 + sc;
            #pragma unroll
            for (int j = 0; j < 4; j++) {
                short8v v = *(const short8v*)&hin[8 * j];
                #pragma unroll
                for (int e = 0; e < 8; e++) {
                    const ushort u = (ushort)v[e];
                    v[e] = (short)((u & 0x8000u) ? 0u : u);   // relu(bf16)
                }
                *(short8v*)&ht[sr][sc + 8 * j] = v;
            }
        }
    }
    // ---- stage wt (128x128): thread -> row tid>>1, 64-elem chunk (tid&1)*64 ----
    {
        const int wr = tid >> 1, wc = (tid & 1) * 64;
        const ushort* src = wt_l + wr * 128 + wc;
        #pragma unroll
        for (int j = 0; j < 8; j++)
            *(short8v*)&wt[wr][wc + 8 * j] = *(const short8v*)&src[8 * j];
    }
    // ---- stage as_ (64x64): thread -> row tid>>2, 16-elem chunk (tid&3)*16 ----
    {
        const int ar = tid >> 2, ac = (tid & 3) * 16;
        const ushort* src = Ab + ar * 64 + ac;
        *(short8v*)&as_[ar][ac]     = *(const short8v*)&src[0];
        *(short8v*)&as_[ar][ac + 8] = *(const short8v*)&src[8];
    }
    __syncthreads();

    // ---- mm1: M = H @ W ; rows s band 16w, all 128 cols, K=128 ----
    {
        f32x4 acc1[8];
        #pragma unroll
        for (int cb = 0; cb < 8; cb++) acc1[cb] = f32x4{0.f, 0.f, 0.f, 0.f};
        short8v af[4];
        #pragma unroll
        for (int ks = 0; ks < 4; ks++)
            af[ks] = *(const short8v*)&ht[16 * w + rf][32 * ks + 8 * q];
        #pragma unroll
        for (int cb = 0; cb < 8; cb++)
            #pragma unroll
            for (int ks = 0; ks < 4; ks++) {
                const short8v bf = *(const short8v*)&wt[16 * cb + rf][32 * ks + 8 * q];
                acc1[cb] = __builtin_amdgcn_mfma_f32_16x16x32_bf16(af[ks], bf, acc1[cb], 0, 0, 0);
            }
        // C layout: col(f)=rf, row(s)=4q+r -> write mT[f][s], 4 consecutive s = ushort4
        #pragma unroll
        for (int cb = 0; cb < 8; cb++)
            *(ushort4*)&mT[16 * cb + rf][16 * w + 4 * q] =
                make_ushort4(f2bf(acc1[cb][0]), f2bf(acc1[cb][1]), f2bf(acc1[cb][2]), f2bf(acc1[cb][3]));
    }
    __syncthreads();

    // ---- mm2: out = Â @ M + bias ; rows d band 16w, K=64 ----
    {
        f32x4 acc2[8];
        #pragma unroll
        for (int cb = 0; cb < 8; cb++) acc2[cb] = f32x4{0.f, 0.f, 0.f, 0.f};
        short8v af2[2];
        #pragma unroll
        for (int ks = 0; ks < 2; ks++)
            af2[ks] = *(const short8v*)&as_[16 * w + rf][32 * ks + 8 * q];
        #pragma unroll
        for (int cb = 0; cb < 8; cb++)
            #pragma unroll
            for (int ks = 0; ks < 2; ks++) {
                const short8v bf2 = *(const short8v*)&mT[16 * cb + rf][32 * ks + 8 * q];
                acc2[cb] = __builtin_amdgcn_mfma_f32_16x16x32_bf16(af2[ks], bf2, acc2[cb], 0, 0, 0);
            }
        #pragma unroll
        for (int cb = 0; cb < 8; cb++) {
            const float bb = bias[16 * cb + rf];
            #pragma unroll
            for (int r = 0; r < 4; r++)
                outp[(16 * w + 4 * q + r) * 128 + 16 * cb + rf] = f2bf(acc2[cb][r] + bb);
        }
    }
}

// ---------------- sims via MFMA: S[l][b] = Q @ C^T, fp32 out ----------------
__global__ __launch_bounds__(256)
void sims_mfma_kernel(const ushort* __restrict__ hq0, const ushort* __restrict__ hc0,
                      const ushort* __restrict__ hq1, const ushort* __restrict__ hc1,
                      const ushort* __restrict__ hq2, const ushort* __restrict__ hc2,
                      float* __restrict__ S)
{
    __shared__ ushort q_s[64][132];
    __shared__ ushort c_s[64][132];
    const int b = blockIdx.x, l = blockIdx.y, tid = threadIdx.x;
    const int lane = tid & 63, w = tid >> 6;
    const int q = lane >> 4, rf = lane & 15;
    const ushort* hq = (l == 0 ? hq0 : (l == 1 ? hq1 : hq2)) + (size_t)b * 8192;
    const ushort* hc = (l == 0 ? hc0 : (l == 1 ? hc1 : hc2)) + (size_t)b * 8192;

    {
        const int sr = tid >> 2, sc = (tid & 3) * 32;
        #pragma unroll
        for (int j = 0; j < 4; j++) {
            *(short8v*)&q_s[sr][sc + 8 * j] = *(const short8v*)&hq[sr * 128 + sc + 8 * j];
            *(short8v*)&c_s[sr][sc + 8 * j] = *(const short8v*)&hc[sr * 128 + sc + 8 * j];
        }
    }
    __syncthreads();

    f32x4 acc[4];
    #pragma unroll
    for (int cb = 0; cb < 4; cb++) acc[cb] = f32x4{0.f, 0.f, 0.f, 0.f};
    short8v af[4];
    #pragma unroll
    for (int ks = 0; ks < 4; ks++)
        af[ks] = *(const short8v*)&q_s[16 * w + rf][32 * ks + 8 * q];
    #pragma unroll
    for (int cb = 0; cb < 4; cb++)
        #pragma unroll
        for (int ks = 0; ks < 4; ks++) {
            const short8v bf = *(const short8v*)&c_s[16 * cb + rf][32 * ks + 8 * q];
            acc[cb] = __builtin_amdgcn_mfma_f32_16x16x32_bf16(af[ks], bf, acc[cb], 0, 0, 0);
        }
    float* out = S + ((size_t)l * NB + b) * 4096;
    #pragma unroll
    for (int cb = 0; cb < 4; cb++)
        #pragma unroll
        for (int r = 0; r < 4; r++)
            out[(16 * w + 4 * q + r) * 64 + 16 * cb + rf] = acc[cb][r];
}

// ---------------- conv1 (fp32, reg-blocked) + conv2 (bf16 implicit-GEMM MFMA) ----------------
__global__ __launch_bounds__(256)
void conv_kernel(const float* __restrict__ simsb,
                 const float* __restrict__ c1w, const float* __restrict__ c1b,
                 const float* __restrict__ c2w, const float* __restrict__ c2b,
                 ushort* __restrict__ featb)
{
    __shared__ float img[68 * 68];          // 18.5KB, 64x64 padded by 2
    __shared__ ushort p1b[36 * 36 * 8];     // 20.7KB
    __shared__ ushort w2s[16][232];         // 7.4KB

    const int b = blockIdx.x, l = blockIdx.y, tid = threadIdx.x;
    const int lane = tid & 63, wid = tid >> 6;
    const int q = lane >> 4, rf = lane & 15;

    for (int i = tid; i < 68 * 68; i += 256) img[i] = 0.f;
    for (int i = tid; i < 36 * 36 * 8 / 2; i += 256) ((uint*)p1b)[i] = 0u;
    for (int i = tid; i < 16 * 224; i += 256) {
        const int co = i / 224, k = i - co * 224;
        const int tap = k >> 3, ci = k & 7;
        w2s[co][k] = (tap < 25) ? f2bf(c2w[l * 3200 + co * 200 + ci * 25 + tap])
                                : (ushort)0;
    }
    __syncthreads();
    for (int i = tid; i < 4096; i += 256) {
        const int y = i >> 6, x = i & 63;
        img[(y + 2) * 68 + (x + 2)] = simsb[((size_t)l * NB + b) * 4096 + i];
    }
    __syncthreads();

    {
        const int by = tid >> 4, bx = tid & 15;
        float pt[8][8];
        #pragma unroll
        for (int r = 0; r < 8; r++)
            #pragma unroll
            for (int c2 = 0; c2 < 4; c2++) {
                const float2 v = *(const float2*)&img[(4 * by + r) * 68 + 4 * bx + 2 * c2];
                pt[r][2 * c2] = v.x; pt[r][2 * c2 + 1] = v.y;
            }
        for (int c = 0; c < 8; c++) {
            float wr[25];
            #pragma unroll
            for (int t = 0; t < 25; t++) wr[t] = c1w[l * 200 + c * 25 + t];
            const float bb = c1b[l * 8 + c];
            #pragma unroll
            for (int jy = 0; jy < 2; jy++)
                #pragma unroll
                for (int jx = 0; jx < 2; jx++) {
                    float m = 0.f;
                    #pragma unroll
                    for (int dy = 0; dy < 2; dy++)
                        #pragma unroll
                        for (int dx = 0; dx < 2; dx++) {
                            float a = bb;
                            #pragma unroll
                            for (int ky = 0; ky < 5; ky++)
                                #pragma unroll
                                for (int kx = 0; kx < 5; kx++)
                                    a += pt[2 * jy + dy + ky][2 * jx + dx + kx] * wr[ky * 5 + kx];
                            m = fmaxf(m, a);
                        }
                    p1b[((2 * by + jy + 2) * 36 + (2 * bx + jx + 2)) * 8 + c] = f2bf(m);
                }
        }
    }
    __syncthreads();

    short8v bf[7];
    #pragma unroll
    for (int ks = 0; ks < 7; ks++)
        bf[ks] = *(const short8v*)&w2s[rf][32 * ks + 8 * q];
    const float bb2 = c2b[l * 16 + rf];

    for (int t = 0; t < 4; t++) {
        const int r = wid + 4 * t;
        f32x4 acc00 = {0.f,0.f,0.f,0.f}, acc01 = acc00, acc10 = acc00, acc11 = acc00;
        #pragma unroll
        for (int ks = 0; ks < 7; ks++) {
            const int tap = 4 * ks + q;
            const int dy = tap / 5, dx = tap - 5 * dy;
            const bool dum = tap >= 25;
            const int row0 = dum ? 35 : (2 * r + dy);
            const int row1 = dum ? 35 : (2 * r + 1 + dy);
            const int cb   = (dum ? 0 : dx) + rf;
            const short8v a00 = *(const short8v*)&p1b[(row0 * 36 + cb) * 8];
            const short8v a01 = *(const short8v*)&p1b[(row0 * 36 + cb + 16) * 8];
            const short8v a10 = *(const short8v*)&p1b[(row1 * 36 + cb) * 8];
            const short8v a11 = *(const short8v*)&p1b[(row1 * 36 + cb + 16) * 8];
            acc00 = __builtin_amdgcn_mfma_f32_16x16x32_bf16(a00, bf[ks], acc00, 0, 0, 0);
            acc01 = __builtin_amdgcn_mfma_f32_16x16x32_bf16(a01, bf[ks], acc01, 0, 0, 0);
            acc10 = __builtin_amdgcn_mfma_f32_16x16x32_bf16(a10, bf[ks], acc10, 0, 0, 0);
            acc11 = __builtin_amdgcn_mfma_f32_16x16x32_bf16(a11, bf[ks], acc11, 0, 0, 0);
        }
        const float v0 = fmaxf(fmaxf(fmaxf(acc00[0], acc00[1]), fmaxf(acc10[0], acc10[1])) + bb2, 0.f);
        const float v1 = fmaxf(fmaxf(fmaxf(acc00[2], acc00[3]), fmaxf(acc10[2], acc10[3])) + bb2, 0.f);
        const float v2 = fmaxf(fmaxf(fmaxf(acc01[0], acc01[1]), fmaxf(acc11[0], acc11[1])) + bb2, 0.f);
        const float v3 = fmaxf(fmaxf(fmaxf(acc01[2], acc01[3]), fmaxf(acc11[2], acc11[3])) + bb2, 0.f);
        const size_t base = (size_t)b * FEAT_F + ((size_t)l * 16 + rf) * 256 + r * 16;
        featb[base + 2 * q]         = f2bf(v0);
        featb[base + 2 * q + 1]     = f2bf(v1);
        featb[base + 8 + 2 * q]     = f2bf(v2);
        featb[base + 8 + 2 * q + 1] = f2bf(v3);
    }
}

// ---------------- cast + transpose lw (12288x512) -> lwT bf16 (512x12288) ----------------
__global__ __launch_bounds__(256)
void cast_lwT_kernel(const float* __restrict__ lw, ushort* __restrict__ lwT)
{
    __shared__ ushort t[32][34];
    const int kb = blockIdx.x * 32, nb2 = blockIdx.y * 32;
    const int x = threadIdx.x & 31, y = threadIdx.x >> 5;
    #pragma unroll
    for (int j = 0; j < 4; j++) {
        const int yy = y + 8 * j;
        t[x][yy] = f2bf(lw[(size_t)(kb + yy) * 512 + nb2 + x]);
    }
    __syncthreads();
    #pragma unroll
    for (int j = 0; j < 4; j++) {
        const int yy = y + 8 * j;
        lwT[(size_t)(nb2 + yy) * FEAT_F + kb + x] = t[yy][x];
    }
}

// ---------------- linear via MFMA: hacc8[kz] = feat_tile @ lw_tile ----------------
__global__ __launch_bounds__(256)
void lin_mfma_kernel(const ushort* __restrict__ featb, const ushort* __restrict__ lwT,
                     float* __restrict__ hacc8)
{
    __shared__ ushort a_s[64][40];
    __shared__ ushort b_s[64][40];
    const int nb = blockIdx.x, mb = blockIdx.y, kz = blockIdx.z;
    const int tid = threadIdx.x;
    const int wid = tid >> 6, lane = tid & 63;
    const int wm = wid >> 1, wn = wid & 1;
    const int m0 = mb * 64, n0 = nb * 64;
    const size_t k0 = (size_t)kz * 1536;

    const int sr = tid >> 2;
    const int sk = (tid & 3) * 8;
    const int kf = (lane >> 4) * 8;
    const int rf = lane & 15;

    f32x4 zero = {0.f, 0.f, 0.f, 0.f};
    f32x4 acc00 = zero, acc01 = zero, acc10 = zero, acc11 = zero;

    for (int ks = 0; ks < 48; ks++) {
        const size_t kc = k0 + (size_t)ks * 32;
        *(short8v*)&a_s[sr][sk] = *(const short8v*)&featb[(size_t)(m0 + sr) * FEAT_F + kc + sk];
        *(short8v*)&b_s[sr][sk] = *(const short8v*)&lwT[(size_t)(n0 + sr) * FEAT_F + kc + sk];
        __syncthreads();
        short8v af0 = *(const short8v*)&a_s[wm * 32 + rf][kf];
        short8v af1 = *(const short8v*)&a_s[wm * 32 + 16 + rf][kf];
        short8v bf0 = *(const short8v*)&b_s[wn * 32 + rf][kf];
        short8v bf1 = *(const short8v*)&b_s[wn * 32 + 16 + rf][kf];
        acc00 = __builtin_amdgcn_mfma_f32_16x16x32_bf16(af0, bf0, acc00, 0, 0, 0);
        acc01 = __builtin_amdgcn_mfma_f32_16x16x32_bf16(af0, bf1, acc01, 0, 0, 0);
        acc10 = __builtin_amdgcn_mfma_f32_16x16x32_bf16(af1, bf0, acc10, 0, 0, 0);
        acc11 = __builtin_amdgcn_mfma_f32_16x16x32_bf16(af1, bf1, acc11, 0, 0, 0);
        __syncthreads();
    }
    float* outz = hacc8 + (size_t)kz * 1024 * 512;
    const int rbase = m0 + wm * 32 + (lane >> 4) * 4;
    const int cbase = n0 + wn * 32 + rf;
    #pragma unroll
    for (int r = 0; r < 4; r++) {
        outz[(size_t)(rbase + r) * 512 + cbase]           = acc00[r];
        outz[(size_t)(rbase + r) * 512 + cbase + 16]      = acc01[r];
        outz[(size_t)(rbase + 16 + r) * 512 + cbase]      = acc10[r];
        outz[(size_t)(rbase + 16 + r) * 512 + cbase + 16] = acc11[r];
    }
}

// ---------------- sum split-K + bias + relu + score dot ----------------
__global__ __launch_bounds__(256)
void score_kernel(const float* __restrict__ hacc8, const float* __restrict__ lb,
                  const float* __restrict__ sw, const float* __restrict__ sb,
                  float* __restrict__ outp)
{
    const int b = blockIdx.x, tid = threadIdx.x;
    float v = 0.f;
    for (int j = tid; j < 512; j += 256) {
        float s = lb[j];
        #pragma unroll
        for (int z = 0; z < 8; z++)
            s += hacc8[((size_t)z * 1024 + b) * 512 + j];
        v += fmaxf(s, 0.f) * sw[j];
    }
    #pragma unroll
    for (int off = 32; off > 0; off >>= 1) v += __shfl_down(v, off);
    __shared__ float red[4];
    if ((tid & 63) == 0) red[tid >> 6] = v;
    __syncthreads();
    if (tid == 0) outp[b] = red[0] + red[1] + red[2] + red[3] + sb[0];
}

extern "C" void kernel_launch(void* const* d_in, const int* in_sizes, int n_in,
                              void* d_out, int out_size, void* d_ws, size_t ws_size,
                              hipStream_t stream)
{
    const float* x_q = (const float*)d_in[0];
    const float* x_c = (const float*)d_in[1];
    const float* gw[3] = {(const float*)d_in[2], (const float*)d_in[4], (const float*)d_in[6]};
    const float* gb[3] = {(const float*)d_in[3], (const float*)d_in[5], (const float*)d_in[7]};
    const float* c1w = (const float*)d_in[8];
    const float* c1b = (const float*)d_in[9];
    const float* c2w = (const float*)d_in[10];
    const float* c2b = (const float*)d_in[11];
    const float* lw  = (const float*)d_in[12];
    const float* lb  = (const float*)d_in[13];
    const float* sw  = (const float*)d_in[14];
    const float* sb  = (const float*)d_in[15];
    const int* eq = (const int*)d_in[16];
    const int* ec = (const int*)d_in[17];

    // Workspace: 222.4 MB total (< cap; 270MB crashed in r2, 237MB ok in r1).
    char* p = (char*)d_ws;
    ushort* hq0 = (ushort*)p; p += (size_t)NB * 8192 * 2;   // 16.78MB each
    ushort* hc0 = (ushort*)p; p += (size_t)NB * 8192 * 2;
    ushort* hq1 = (ushort*)p; p += (size_t)NB * 8192 * 2;
    ushort* hc1 = (ushort*)p; p += (size_t)NB * 8192 * 2;
    ushort* hq2 = (ushort*)p; p += (size_t)NB * 8192 * 2;
    ushort* hc2 = (ushort*)p; p += (size_t)NB * 8192 * 2;
    ushort* Aqb = (ushort*)p; p += (size_t)NB * 4096 * 2;   // 8.39MB
    ushort* Acb = (ushort*)p; p += (size_t)NB * 4096 * 2;
    ushort* wtb = (ushort*)p; p += (size_t)3 * ND * ND * 2; // 98KB
    float* simsb = (float*)p; p += (size_t)3 * NB * 4096 * 4;  // 50.3MB
    float* hacc8 = (float*)p; p += (size_t)8 * NB * 512 * 4;   // 16.8MB
    ushort* featb = (ushort*)p; p += (size_t)NB * FEAT_F * 2;  // 25.2MB
    ushort* lwT   = (ushort*)p; p += (size_t)512 * FEAT_F * 2; // 12.6MB
    float* outf = (float*)d_out;

    const int* esq = eq;
    const int* edq = eq + (size_t)NB * NE;
    const int* esc = ec;
    const int* edc = ec + (size_t)NB * NE;

    adj_kernel<<<dim3(NB, 2), 256, 0, stream>>>(esq, edq, esc, edc, Aqb, Acb);
    castw_kernel<<<3, 256, 0, stream>>>(gw[0], gw[1], gw[2], wtb);
    cast_lwT_kernel<<<dim3(FEAT_F / 32, 512 / 32), 256, 0, stream>>>(lw, lwT);

    gcn_mfma_kernel<<<dim3(NB, 2), 256, 0, stream>>>(x_q, x_c, Aqb, Acb, wtb,
                                                     gb[0], hq0, hc0, 1);
    gcn_mfma_kernel<<<dim3(NB, 2), 256, 0, stream>>>(hq0, hc0, Aqb, Acb, wtb + ND * ND,
                                                     gb[1], hq1, hc1, 0);
    gcn_mfma_kernel<<<dim3(NB, 2), 256, 0, stream>>>(hq1, hc1, Aqb, Acb, wtb + 2 * ND * ND,
                                                     gb[2], hq2, hc2, 0);

    sims_mfma_kernel<<<dim3(NB, 3), 256, 0, stream>>>(hq0, hc0, hq1, hc1, hq2, hc2, simsb);

    conv_kernel<<<dim3(NB, 3), 256, 0, stream>>>(simsb, c1w, c1b, c2w, c2b, featb);

    lin_mfma_kernel<<<dim3(8, 16, 8), 256, 0, stream>>>(featb, lwT, hacc8);
    score_kernel<<<NB, 256, 0, stream>>>(hacc8, lb, sw, sb, outf);
}

// Round 11
// 404.714 us; speedup vs baseline: 8.2666x; 1.0099x over previous
//
#include <hip/hip_runtime.h>

constexpr int NB = 1024;   // graphs
constexpr int NN = 64;     // nodes per graph
constexpr int ND = 128;    // feature dim (D == G == 128)
constexpr int NE = 512;    // edges per graph
constexpr int FEAT_F = 12288;  // 3*16*16*16

typedef __attribute__((ext_vector_type(8))) short short8v;   // 8 bf16 (4 VGPRs)
typedef __attribute__((ext_vector_type(4))) float f32x4;
typedef __fp16 h2v __attribute__((ext_vector_type(2)));      // matches cvt_pkrtz/fdot2

__device__ inline ushort f2bf(float x) {                      // fp32 -> bf16 RNE
    unsigned u = __float_as_uint(x);
    u += 0x7FFFu + ((u >> 16) & 1u);
    return (ushort)(u >> 16);
}

// ---------------- build normalized adjacency Â (bf16) per (graph, side) ----------------
__global__ __launch_bounds__(256)
void adj_kernel(const int* __restrict__ esq, const int* __restrict__ edq,
                const int* __restrict__ esc, const int* __restrict__ edc,
                ushort* __restrict__ Aq, ushort* __restrict__ Ac)
{
    __shared__ float A[NN * NN];
    __shared__ float dis[NN];
    const int b = blockIdx.x, side = blockIdx.y, tid = threadIdx.x;
    const int* es = side ? esc : esq;
    const int* ed = side ? edc : edq;
    ushort* Aout = side ? Ac : Aq;

    for (int i = tid; i < NN * NN; i += 256) A[i] = 0.f;
    __syncthreads();
    for (int e = tid; e < NE; e += 256) {
        const int s = es[b * NE + e] & (NN - 1);
        const int d = ed[b * NE + e] & (NN - 1);
        atomicAdd(&A[d * NN + s], 1.0f);
    }
    __syncthreads();
    if (tid < NN) {
        float sum = 1.0f;                       // self loop
        for (int s = 0; s < NN; s++) sum += A[tid * NN + s];
        dis[tid] = rsqrtf(sum);
    }
    __syncthreads();
    for (int i = tid; i < NN * NN; i += 256) {
        const int d = i >> 6, s = i & 63;
        float v = A[i];
        if (d == s) v += 1.0f;                  // self loop
        Aout[(size_t)b * (NN * NN) + i] = f2bf(dis[d] * v * dis[s]);
    }
}

// ---------------- cast+transpose gcn weights: wtb[l][f][k] = bf16(W_l[k][f]) ----------------
__global__ __launch_bounds__(256)
void castw_kernel(const float* __restrict__ w0, const float* __restrict__ w1,
                  const float* __restrict__ w2, ushort* __restrict__ wtb)
{
    const float* W = blockIdx.x == 0 ? w0 : (blockIdx.x == 1 ? w1 : w2);
    ushort* out = wtb + (size_t)blockIdx.x * ND * ND;
    for (int i = threadIdx.x; i < ND * ND; i += 256) {
        const int f = i >> 7, k = i & 127;
        out[i] = f2bf(W[k * ND + f]);
    }
}

// ---------------- GCN layer via MFMA: out = Â @ (relu?(H) @ W) + b, bf16 ----------------
__global__ __launch_bounds__(256)
void gcn_mfma_kernel(const void* __restrict__ hq_in, const void* __restrict__ hc_in,
                     const ushort* __restrict__ Aqb, const ushort* __restrict__ Acb,
                     const ushort* __restrict__ wt_l, const float* __restrict__ bias,
                     ushort* __restrict__ outq, ushort* __restrict__ outc, int first)
{
    __shared__ ushort ht[64][132];     // H bf16 (relu'd), 16.9KB
    __shared__ ushort wt[128][132];    // W^T [f][k], 33.8KB
    __shared__ ushort mT[128][68];     // M^T [f][s], 17.4KB
    __shared__ ushort as_[64][68];     // Â [d][s], 8.7KB

    const int b = blockIdx.x, side = blockIdx.y, tid = threadIdx.x;
    const int lane = tid & 63, w = tid >> 6;
    const int q = lane >> 4, rf = lane & 15;

    const ushort* Ab = (side ? Acb : Aqb) + (size_t)b * 4096;
    ushort* outp = (side ? outc : outq) + (size_t)b * 8192;

    {
        const int sr = tid >> 2, sc = (tid & 3) * 32;
        if (first) {
            const float* hin = (const float*)(side ? hc_in : hq_in) + (size_t)b * 8192 + sr * 128 + sc;
            #pragma unroll
            for (int j = 0; j < 4; j++) {
                const float4 v0 = *(const float4*)&hin[8 * j];
                const float4 v1 = *(const float4*)&hin[8 * j + 4];
                *(ushort4*)&ht[sr][sc + 8 * j]     = make_ushort4(f2bf(v0.x), f2bf(v0.y), f2bf(v0.z), f2bf(v0.w));
                *(ushort4*)&ht[sr][sc + 8 * j + 4] = make_ushort4(f2bf(v1.x), f2bf(v1.y), f2bf(v1.z), f2bf(v1.w));
            }
        } else {
            const ushort* hin = (const ushort*)(side ? hc_in : hq_in) + (size_t)b * 8192 + sr * 128 + sc;
            #pragma unroll
            for (int j = 0; j < 4; j++) {
                short8v v = *(const short8v*)&hin[8 * j];
                #pragma unroll
                for (int e = 0; e < 8; e++) {
                    const ushort u = (ushort)v[e];
                    v[e] = (short)((u & 0x8000u) ? 0u : u);   // relu(bf16)
                }
                *(short8v*)&ht[sr][sc + 8 * j] = v;
            }
        }
    }
    {
        const int wr = tid >> 1, wc = (tid & 1) * 64;
        const ushort* src = wt_l + wr * 128 + wc;
        #pragma unroll
        for (int j = 0; j < 8; j++)
            *(short8v*)&wt[wr][wc + 8 * j] = *(const short8v*)&src[8 * j];
    }
    {
        const int ar = tid >> 2, ac = (tid & 3) * 16;
        const ushort* src = Ab + ar * 64 + ac;
        *(short8v*)&as_[ar][ac]     = *(const short8v*)&src[0];
        *(short8v*)&as_[ar][ac + 8] = *(const short8v*)&src[8];
    }
    __syncthreads();

    {
        f32x4 acc1[8];
        #pragma unroll
        for (int cb = 0; cb < 8; cb++) acc1[cb] = f32x4{0.f, 0.f, 0.f, 0.f};
        short8v af[4];
        #pragma unroll
        for (int ks = 0; ks < 4; ks++)
            af[ks] = *(const short8v*)&ht[16 * w + rf][32 * ks + 8 * q];
        #pragma unroll
        for (int cb = 0; cb < 8; cb++)
            #pragma unroll
            for (int ks = 0; ks < 4; ks++) {
                const short8v bf = *(const short8v*)&wt[16 * cb + rf][32 * ks + 8 * q];
                acc1[cb] = __builtin_amdgcn_mfma_f32_16x16x32_bf16(af[ks], bf, acc1[cb], 0, 0, 0);
            }
        #pragma unroll
        for (int cb = 0; cb < 8; cb++)
            *(ushort4*)&mT[16 * cb + rf][16 * w + 4 * q] =
                make_ushort4(f2bf(acc1[cb][0]), f2bf(acc1[cb][1]), f2bf(acc1[cb][2]), f2bf(acc1[cb][3]));
    }
    __syncthreads();

    {
        f32x4 acc2[8];
        #pragma unroll
        for (int cb = 0; cb < 8; cb++) acc2[cb] = f32x4{0.f, 0.f, 0.f, 0.f};
        short8v af2[2];
        #pragma unroll
        for (int ks = 0; ks < 2; ks++)
            af2[ks] = *(const short8v*)&as_[16 * w + rf][32 * ks + 8 * q];
        #pragma unroll
        for (int cb = 0; cb < 8; cb++)
            #pragma unroll
            for (int ks = 0; ks < 2; ks++) {
                const short8v bf2 = *(const short8v*)&mT[16 * cb + rf][32 * ks + 8 * q];
                acc2[cb] = __builtin_amdgcn_mfma_f32_16x16x32_bf16(af2[ks], bf2, acc2[cb], 0, 0, 0);
            }
        #pragma unroll
        for (int cb = 0; cb < 8; cb++) {
            const float bb = bias[16 * cb + rf];
            #pragma unroll
            for (int r = 0; r < 4; r++)
                outp[(16 * w + 4 * q + r) * 128 + 16 * cb + rf] = f2bf(acc2[cb][r] + bb);
        }
    }
}

// ---------------- sims via MFMA: S[l][b] = Q @ C^T, fp32 out ----------------
__global__ __launch_bounds__(256)
void sims_mfma_kernel(const ushort* __restrict__ hq0, const ushort* __restrict__ hc0,
                      const ushort* __restrict__ hq1, const ushort* __restrict__ hc1,
                      const ushort* __restrict__ hq2, const ushort* __restrict__ hc2,
                      float* __restrict__ S)
{
    __shared__ ushort q_s[64][132];
    __shared__ ushort c_s[64][132];
    const int b = blockIdx.x, l = blockIdx.y, tid = threadIdx.x;
    const int lane = tid & 63, w = tid >> 6;
    const int q = lane >> 4, rf = lane & 15;
    const ushort* hq = (l == 0 ? hq0 : (l == 1 ? hq1 : hq2)) + (size_t)b * 8192;
    const ushort* hc = (l == 0 ? hc0 : (l == 1 ? hc1 : hc2)) + (size_t)b * 8192;

    {
        const int sr = tid >> 2, sc = (tid & 3) * 32;
        #pragma unroll
        for (int j = 0; j < 4; j++) {
            *(short8v*)&q_s[sr][sc + 8 * j] = *(const short8v*)&hq[sr * 128 + sc + 8 * j];
            *(short8v*)&c_s[sr][sc + 8 * j] = *(const short8v*)&hc[sr * 128 + sc + 8 * j];
        }
    }
    __syncthreads();

    f32x4 acc[4];
    #pragma unroll
    for (int cb = 0; cb < 4; cb++) acc[cb] = f32x4{0.f, 0.f, 0.f, 0.f};
    short8v af[4];
    #pragma unroll
    for (int ks = 0; ks < 4; ks++)
        af[ks] = *(const short8v*)&q_s[16 * w + rf][32 * ks + 8 * q];
    #pragma unroll
    for (int cb = 0; cb < 4; cb++)
        #pragma unroll
        for (int ks = 0; ks < 4; ks++) {
            const short8v bf = *(const short8v*)&c_s[16 * cb + rf][32 * ks + 8 * q];
            acc[cb] = __builtin_amdgcn_mfma_f32_16x16x32_bf16(af[ks], bf, acc[cb], 0, 0, 0);
        }
    float* out = S + ((size_t)l * NB + b) * 4096;
    #pragma unroll
    for (int cb = 0; cb < 4; cb++)
        #pragma unroll
        for (int r = 0; r < 4; r++)
            out[(16 * w + 4 * q + r) * 64 + 16 * cb + rf] = acc[cb][r];
}

// ---------------- conv1 (f16 dot2, reg-blocked) + conv2 (bf16 implicit-GEMM MFMA) ----------------
__global__ __launch_bounds__(256)
void conv_kernel(const float* __restrict__ simsb,
                 const float* __restrict__ c1w, const float* __restrict__ c1b,
                 const float* __restrict__ c2w, const float* __restrict__ c2b,
                 ushort* __restrict__ featb)
{
    __shared__ float img[68 * 68];          // 18.5KB, 64x64 padded by 2
    __shared__ ushort p1b[36 * 36 * 8];     // 20.7KB
    __shared__ ushort w2s[16][232];         // 7.4KB

    const int b = blockIdx.x, l = blockIdx.y, tid = threadIdx.x;
    const int lane = tid & 63, wid = tid >> 6;
    const int q = lane >> 4, rf = lane & 15;

    for (int i = tid; i < 68 * 68; i += 256) img[i] = 0.f;
    for (int i = tid; i < 36 * 36 * 8 / 2; i += 256) ((uint*)p1b)[i] = 0u;
    for (int i = tid; i < 16 * 224; i += 256) {
        const int co = i / 224, k = i - co * 224;
        const int tap = k >> 3, ci = k & 7;
        w2s[co][k] = (tap < 25) ? f2bf(c2w[l * 3200 + co * 200 + ci * 25 + tap])
                                : (ushort)0;
    }
    __syncthreads();
    for (int i = tid; i < 4096; i += 256) {
        const int y = i >> 6, x = i & 63;
        img[(y + 2) * 68 + (x + 2)] = simsb[((size_t)l * NB + b) * 4096 + i];
    }
    __syncthreads();

    // ---- conv1: thread owns 2x2 POOLED outputs at (2by+jy, 2bx+jx); 8x8 patch ----
    {
        const int by = tid >> 4, bx = tid & 15;
        float mv[2][2][8];                   // [jy][jx][cout] pooled+relu'd results
#if __has_builtin(__builtin_amdgcn_fdot2)
        // pack patch rows into even/odd-phase half2 (f16): X even reads pe, odd reads po
        h2v pe[8][4], po[8][4];
        #pragma unroll
        for (int r = 0; r < 8; r++) {
            float x[8];
            #pragma unroll
            for (int c2 = 0; c2 < 4; c2++) {
                const float2 v = *(const float2*)&img[(4 * by + r) * 68 + 4 * bx + 2 * c2];
                x[2 * c2] = v.x; x[2 * c2 + 1] = v.y;
            }
            #pragma unroll
            for (int m = 0; m < 4; m++) {
                pe[r][m] = __builtin_amdgcn_cvt_pkrtz(x[2 * m], x[2 * m + 1]);
                po[r][m] = __builtin_amdgcn_cvt_pkrtz(x[2 * m + 1], (m < 3) ? x[2 * m + 2] : x[7]);
            }
        }
        for (int c = 0; c < 8; c++) {
            h2v wp[5][3];                    // weight pairs (phase-independent)
            #pragma unroll
            for (int ky = 0; ky < 5; ky++) {
                const float w0 = c1w[l * 200 + c * 25 + 5 * ky];
                const float w1 = c1w[l * 200 + c * 25 + 5 * ky + 1];
                const float w2 = c1w[l * 200 + c * 25 + 5 * ky + 2];
                const float w3 = c1w[l * 200 + c * 25 + 5 * ky + 3];
                const float w4 = c1w[l * 200 + c * 25 + 5 * ky + 4];
                wp[ky][0] = __builtin_amdgcn_cvt_pkrtz(w0, w1);
                wp[ky][1] = __builtin_amdgcn_cvt_pkrtz(w2, w3);
                wp[ky][2] = __builtin_amdgcn_cvt_pkrtz(w4, 0.f);
            }
            const float bb = c1b[l * 8 + c];
            #pragma unroll
            for (int jy = 0; jy < 2; jy++)
                #pragma unroll
                for (int jx = 0; jx < 2; jx++) {
                    float mm = 0.f;          // relu floor
                    #pragma unroll
                    for (int dy = 0; dy < 2; dy++)
                        #pragma unroll
                        for (int dx = 0; dx < 2; dx++) {
                            const int Y = 2 * jy + dy, X = 2 * jx + dx, m0 = X >> 1;
                            float a = bb;
                            #pragma unroll
                            for (int ky = 0; ky < 5; ky++) {
                                if (X & 1) {
                                    a = __builtin_amdgcn_fdot2(po[Y + ky][m0],     wp[ky][0], a, false);
                                    a = __builtin_amdgcn_fdot2(po[Y + ky][m0 + 1], wp[ky][1], a, false);
                                    a = __builtin_amdgcn_fdot2(po[Y + ky][m0 + 2], wp[ky][2], a, false);
                                } else {
                                    a = __builtin_amdgcn_fdot2(pe[Y + ky][m0],     wp[ky][0], a, false);
                                    a = __builtin_amdgcn_fdot2(pe[Y + ky][m0 + 1], wp[ky][1], a, false);
                                    a = __builtin_amdgcn_fdot2(pe[Y + ky][m0 + 2], wp[ky][2], a, false);
                                }
                            }
                            mm = fmaxf(mm, a);
                        }
                    mv[jy][jx][c] = mm;
                }
        }
#else
        float pt[8][8];
        #pragma unroll
        for (int r = 0; r < 8; r++)
            #pragma unroll
            for (int c2 = 0; c2 < 4; c2++) {
                const float2 v = *(const float2*)&img[(4 * by + r) * 68 + 4 * bx + 2 * c2];
                pt[r][2 * c2] = v.x; pt[r][2 * c2 + 1] = v.y;
            }
        for (int c = 0; c < 8; c++) {
            float wr[25];
            #pragma unroll
            for (int t = 0; t < 25; t++) wr[t] = c1w[l * 200 + c * 25 + t];
            const float bb = c1b[l * 8 + c];
            #pragma unroll
            for (int jy = 0; jy < 2; jy++)
                #pragma unroll
                for (int jx = 0; jx < 2; jx++) {
                    float mm = 0.f;
                    #pragma unroll
                    for (int dy = 0; dy < 2; dy++)
                        #pragma unroll
                        for (int dx = 0; dx < 2; dx++) {
                            float a = bb;
                            #pragma unroll
                            for (int ky = 0; ky < 5; ky++)
                                #pragma unroll
                                for (int kx = 0; kx < 5; kx++)
                                    a += pt[2 * jy + dy + ky][2 * jx + dx + kx] * wr[ky * 5 + kx];
                            mm = fmaxf(mm, a);
                        }
                    mv[jy][jx][c] = mm;
                }
        }
#endif
        // vectorized p1b writes: one 16B store per pooled position (8 couts)
        #pragma unroll
        for (int jy = 0; jy < 2; jy++)
            #pragma unroll
            for (int jx = 0; jx < 2; jx++) {
                const int pos = (2 * by + jy + 2) * 36 + (2 * bx + jx + 2);
                *(ushort4*)&p1b[pos * 8] =
                    make_ushort4(f2bf(mv[jy][jx][0]), f2bf(mv[jy][jx][1]),
                                 f2bf(mv[jy][jx][2]), f2bf(mv[jy][jx][3]));
                *(ushort4*)&p1b[pos * 8 + 4] =
                    make_ushort4(f2bf(mv[jy][jx][4]), f2bf(mv[jy][jx][5]),
                                 f2bf(mv[jy][jx][6]), f2bf(mv[jy][jx][7]));
            }
    }
    __syncthreads();

    // ---- conv2 MFMA: wave handles y-pairs r = wid+4t ----
    short8v bf[7];
    #pragma unroll
    for (int ks = 0; ks < 7; ks++)
        bf[ks] = *(const short8v*)&w2s[rf][32 * ks + 8 * q];
    const float bb2 = c2b[l * 16 + rf];

    for (int t = 0; t < 4; t++) {
        const int r = wid + 4 * t;
        f32x4 acc00 = {0.f,0.f,0.f,0.f}, acc01 = acc00, acc10 = acc00, acc11 = acc00;
        #pragma unroll
        for (int ks = 0; ks < 7; ks++) {
            const int tap = 4 * ks + q;
            const int dy = tap / 5, dx = tap - 5 * dy;
            const bool dum = tap >= 25;
            const int row0 = dum ? 35 : (2 * r + dy);
            const int row1 = dum ? 35 : (2 * r + 1 + dy);
            const int cb   = (dum ? 0 : dx) + rf;
            const short8v a00 = *(const short8v*)&p1b[(row0 * 36 + cb) * 8];
            const short8v a01 = *(const short8v*)&p1b[(row0 * 36 + cb + 16) * 8];
            const short8v a10 = *(const short8v*)&p1b[(row1 * 36 + cb) * 8];
            const short8v a11 = *(const short8v*)&p1b[(row1 * 36 + cb + 16) * 8];
            acc00 = __builtin_amdgcn_mfma_f32_16x16x32_bf16(a00, bf[ks], acc00, 0, 0, 0);
            acc01 = __builtin_amdgcn_mfma_f32_16x16x32_bf16(a01, bf[ks], acc01, 0, 0, 0);
            acc10 = __builtin_amdgcn_mfma_f32_16x16x32_bf16(a10, bf[ks], acc10, 0, 0, 0);
            acc11 = __builtin_amdgcn_mfma_f32_16x16x32_bf16(a11, bf[ks], acc11, 0, 0, 0);
        }
        const float v0 = fmaxf(fmaxf(fmaxf(acc00[0], acc00[1]), fmaxf(acc10[0], acc10[1])) + bb2, 0.f);
        const float v1 = fmaxf(fmaxf(fmaxf(acc00[2], acc00[3]), fmaxf(acc10[2], acc10[3])) + bb2, 0.f);
        const float v2 = fmaxf(fmaxf(fmaxf(acc01[0], acc01[1]), fmaxf(acc11[0], acc11[1])) + bb2, 0.f);
        const float v3 = fmaxf(fmaxf(fmaxf(acc01[2], acc01[3]), fmaxf(acc11[2], acc11[3])) + bb2, 0.f);
        const size_t base = (size_t)b * FEAT_F + ((size_t)l * 16 + rf) * 256 + r * 16;
        featb[base + 2 * q]         = f2bf(v0);
        featb[base + 2 * q + 1]     = f2bf(v1);
        featb[base + 8 + 2 * q]     = f2bf(v2);
        featb[base + 8 + 2 * q + 1] = f2bf(v3);
    }
}

// ---------------- cast + transpose lw (12288x512) -> lwT bf16 (512x12288) ----------------
__global__ __launch_bounds__(256)
void cast_lwT_kernel(const float* __restrict__ lw, ushort* __restrict__ lwT)
{
    __shared__ ushort t[32][34];
    const int kb = blockIdx.x * 32, nb2 = blockIdx.y * 32;
    const int x = threadIdx.x & 31, y = threadIdx.x >> 5;
    #pragma unroll
    for (int j = 0; j < 4; j++) {
        const int yy = y + 8 * j;
        t[x][yy] = f2bf(lw[(size_t)(kb + yy) * 512 + nb2 + x]);
    }
    __syncthreads();
    #pragma unroll
    for (int j = 0; j < 4; j++) {
        const int yy = y + 8 * j;
        lwT[(size_t)(nb2 + yy) * FEAT_F + kb + x] = t[yy][x];
    }
}

// ---------------- linear via MFMA: hacc8[kz] = feat_tile @ lw_tile ----------------
__global__ __launch_bounds__(256)
void lin_mfma_kernel(const ushort* __restrict__ featb, const ushort* __restrict__ lwT,
                     float* __restrict__ hacc8)
{
    __shared__ ushort a_s[64][40];
    __shared__ ushort b_s[64][40];
    const int nb = blockIdx.x, mb = blockIdx.y, kz = blockIdx.z;
    const int tid = threadIdx.x;
    const int wid = tid >> 6, lane = tid & 63;
    const int wm = wid >> 1, wn = wid & 1;
    const int m0 = mb * 64, n0 = nb * 64;
    const size_t k0 = (size_t)kz * 1536;

    const int sr = tid >> 2;
    const int sk = (tid & 3) * 8;
    const int kf = (lane >> 4) * 8;
    const int rf = lane & 15;

    f32x4 zero = {0.f, 0.f, 0.f, 0.f};
    f32x4 acc00 = zero, acc01 = zero, acc10 = zero, acc11 = zero;

    for (int ks = 0; ks < 48; ks++) {
        const size_t kc = k0 + (size_t)ks * 32;
        *(short8v*)&a_s[sr][sk] = *(const short8v*)&featb[(size_t)(m0 + sr) * FEAT_F + kc + sk];
        *(short8v*)&b_s[sr][sk] = *(const short8v*)&lwT[(size_t)(n0 + sr) * FEAT_F + kc + sk];
        __syncthreads();
        short8v af0 = *(const short8v*)&a_s[wm * 32 + rf][kf];
        short8v af1 = *(const short8v*)&a_s[wm * 32 + 16 + rf][kf];
        short8v bf0 = *(const short8v*)&b_s[wn * 32 + rf][kf];
        short8v bf1 = *(const short8v*)&b_s[wn * 32 + 16 + rf][kf];
        acc00 = __builtin_amdgcn_mfma_f32_16x16x32_bf16(af0, bf0, acc00, 0, 0, 0);
        acc01 = __builtin_amdgcn_mfma_f32_16x16x32_bf16(af0, bf1, acc01, 0, 0, 0);
        acc10 = __builtin_amdgcn_mfma_f32_16x16x32_bf16(af1, bf0, acc10, 0, 0, 0);
        acc11 = __builtin_amdgcn_mfma_f32_16x16x32_bf16(af1, bf1, acc11, 0, 0, 0);
        __syncthreads();
    }
    float* outz = hacc8 + (size_t)kz * 1024 * 512;
    const int rbase = m0 + wm * 32 + (lane >> 4) * 4;
    const int cbase = n0 + wn * 32 + rf;
    #pragma unroll
    for (int r = 0; r < 4; r++) {
        outz[(size_t)(rbase + r) * 512 + cbase]           = acc00[r];
        outz[(size_t)(rbase + r) * 512 + cbase + 16]      = acc01[r];
        outz[(size_t)(rbase + 16 + r) * 512 + cbase]      = acc10[r];
        outz[(size_t)(rbase + 16 + r) * 512 + cbase + 16] = acc11[r];
    }
}

// ---------------- sum split-K + bias + relu + score dot ----------------
__global__ __launch_bounds__(256)
void score_kernel(const float* __restrict__ hacc8, const float* __restrict__ lb,
                  const float* __restrict__ sw, const float* __restrict__ sb,
                  float* __restrict__ outp)
{
    const int b = blockIdx.x, tid = threadIdx.x;
    float v = 0.f;
    for (int j = tid; j < 512; j += 256) {
        float s = lb[j];
        #pragma unroll
        for (int z = 0; z < 8; z++)
            s += hacc8[((size_t)z * 1024 + b) * 512 + j];
        v += fmaxf(s, 0.f) * sw[j];
    }
    #pragma unroll
    for (int off = 32; off > 0; off >>= 1) v += __shfl_down(v, off);
    __shared__ float red[4];
    if ((tid & 63) == 0) red[tid >> 6] = v;
    __syncthreads();
    if (tid == 0) outp[b] = red[0] + red[1] + red[2] + red[3] + sb[0];
}

extern "C" void kernel_launch(void* const* d_in, const int* in_sizes, int n_in,
                              void* d_out, int out_size, void* d_ws, size_t ws_size,
                              hipStream_t stream)
{
    const float* x_q = (const float*)d_in[0];
    const float* x_c = (const float*)d_in[1];
    const float* gw[3] = {(const float*)d_in[2], (const float*)d_in[4], (const float*)d_in[6]};
    const float* gb[3] = {(const float*)d_in[3], (const float*)d_in[5], (const float*)d_in[7]};
    const float* c1w = (const float*)d_in[8];
    const float* c1b = (const float*)d_in[9];
    const float* c2w = (const float*)d_in[10];
    const float* c2b = (const float*)d_in[11];
    const float* lw  = (const float*)d_in[12];
    const float* lb  = (const float*)d_in[13];
    const float* sw  = (const float*)d_in[14];
    const float* sb  = (const float*)d_in[15];
    const int* eq = (const int*)d_in[16];
    const int* ec = (const int*)d_in[17];

    // Workspace: 222.4 MB total (< cap; 270MB crashed in r2, 237MB ok in r1).
    char* p = (char*)d_ws;
    ushort* hq0 = (ushort*)p; p += (size_t)NB * 8192 * 2;
    ushort* hc0 = (ushort*)p; p += (size_t)NB * 8192 * 2;
    ushort* hq1 = (ushort*)p; p += (size_t)NB * 8192 * 2;
    ushort* hc1 = (ushort*)p; p += (size_t)NB * 8192 * 2;
    ushort* hq2 = (ushort*)p; p += (size_t)NB * 8192 * 2;
    ushort* hc2 = (ushort*)p; p += (size_t)NB * 8192 * 2;
    ushort* Aqb = (ushort*)p; p += (size_t)NB * 4096 * 2;
    ushort* Acb = (ushort*)p; p += (size_t)NB * 4096 * 2;
    ushort* wtb = (ushort*)p; p += (size_t)3 * ND * ND * 2;
    float* simsb = (float*)p; p += (size_t)3 * NB * 4096 * 4;
    float* hacc8 = (float*)p; p += (size_t)8 * NB * 512 * 4;
    ushort* featb = (ushort*)p; p += (size_t)NB * FEAT_F * 2;
    ushort* lwT   = (ushort*)p; p += (size_t)512 * FEAT_F * 2;
    float* outf = (float*)d_out;

    const int* esq = eq;
    const int* edq = eq + (size_t)NB * NE;
    const int* esc = ec;
    const int* edc = ec + (size_t)NB * NE;

    adj_kernel<<<dim3(NB, 2), 256, 0, stream>>>(esq, edq, esc, edc, Aqb, Acb);
    castw_kernel<<<3, 256, 0, stream>>>(gw[0], gw[1], gw[2], wtb);
    cast_lwT_kernel<<<dim3(FEAT_F / 32, 512 / 32), 256, 0, stream>>>(lw, lwT);

    gcn_mfma_kernel<<<dim3(NB, 2), 256, 0, stream>>>(x_q, x_c, Aqb, Acb, wtb,
                                                     gb[0], hq0, hc0, 1);
    gcn_mfma_kernel<<<dim3(NB, 2), 256, 0, stream>>>(hq0, hc0, Aqb, Acb, wtb + ND * ND,
                                                     gb[1], hq1, hc1, 0);
    gcn_mfma_kernel<<<dim3(NB, 2), 256, 0, stream>>>(hq1, hc1, Aqb, Acb, wtb + 2 * ND * ND,
                                                     gb[2], hq2, hc2, 0);

    sims_mfma_kernel<<<dim3(NB, 3), 256, 0, stream>>>(hq0, hc0, hq1, hc1, hq2, hc2, simsb);

    conv_kernel<<<dim3(NB, 3), 256, 0, stream>>>(simsb, c1w, c1b, c2w, c2b, featb);

    lin_mfma_kernel<<<dim3(8, 16, 8), 256, 0, stream>>>(featb, lwT, hacc8);
    score_kernel<<<NB, 256, 0, stream>>>(hacc8, lb, sw, sb, outf);
}